// Round 1
// 465.390 us; speedup vs baseline: 1.0536x; 1.0536x over previous
//
#include <hip/hip_runtime.h>
#include <stdint.h>

// Problem constants (fixed shapes)
#define DIMX 4096
#define NH   32
#define NKV  8
#define HD   128
#define SEQ  2048
#define QKVD 6144   // 4096 q + 1024 k + 1024 v

typedef _Float16 h16;
typedef __attribute__((ext_vector_type(8))) _Float16 h16x8;
typedef __attribute__((ext_vector_type(4))) _Float16 h16x4;
typedef __attribute__((ext_vector_type(4))) float   f32x4;

__device__ __forceinline__ void gload_lds16(const void* g, void* l) {
  __builtin_amdgcn_global_load_lds(
      (const __attribute__((address_space(1))) void*)g,
      (__attribute__((address_space(3))) void*)l, 16, 0, 0);
}

// ---- 16-lane reductions on the VALU via DPP reversal butterflies (no LDS pipe) ----
template <int CTRL>
__device__ __forceinline__ float dpp_mv(float x) {
  int y = __builtin_amdgcn_mov_dpp(__builtin_bit_cast(int, x), CTRL, 0xF, 0xF, true);
  return __builtin_bit_cast(float, y);
}
__device__ __forceinline__ float red16_max(float x) {
  x = fmaxf(x, dpp_mv<0xB1>(x));   // rev2
  x = fmaxf(x, dpp_mv<0x1B>(x));   // rev4
  x = fmaxf(x, dpp_mv<0x141>(x));  // rev8
  x = fmaxf(x, dpp_mv<0x140>(x));  // rev16
  return x;
}
__device__ __forceinline__ float red16_sum(float x) {
  x += dpp_mv<0xB1>(x);
  x += dpp_mv<0x1B>(x);
  x += dpp_mv<0x141>(x);
  x += dpp_mv<0x140>(x);
  return x;
}

// ---------- fused dequant (all 4 weights) + x cast ----------
__device__ __forceinline__ void dq_unit(const void* __restrict__ w, const float* __restrict__ sc,
                                        h16* __restrict__ out, int u, int flag) {
  uint32_t b4;
  if (flag) {
    const int4 t = *(const int4*)((const int*)w + 4 * u);
    b4 = (uint32_t)(t.x & 0xFF) | ((uint32_t)(t.y & 0xFF) << 8) |
         ((uint32_t)(t.z & 0xFF) << 16) | ((uint32_t)(t.w & 0xFF) << 24);
  } else {
    b4 = ((const uint32_t*)w)[u];
  }
  int r = u >> 4;
  int p = (u & 15) * 4;
  float shi = sc[2 * r], slo = sc[2 * r + 1];
  h16x4 hi, lo;
#pragma unroll
  for (int j = 0; j < 4; ++j) {
    int by = (int)((b4 >> (8 * j)) & 0xFF);
    int hn = (by << 24) >> 28;
    int ln = (by << 28) >> 28;
    hi[j] = (h16)((float)hn * shi);
    lo[j] = (h16)((float)ln * slo);
  }
  *(h16x4*)(out + (r << 7) + p)      = hi;
  *(h16x4*)(out + (r << 7) + 64 + p) = lo;
}

#define U_WQ 2097152
#define U_WK 524288
#define U_WV 524288
#define U_WO 2097152

__global__ __launch_bounds__(256) void prep_all(
    const void* __restrict__ wq, const float* __restrict__ sq,
    const void* __restrict__ wk, const float* __restrict__ sk,
    const void* __restrict__ wv, const float* __restrict__ sv,
    const void* __restrict__ wo, const float* __restrict__ so,
    const float4* __restrict__ x,
    h16* __restrict__ Wqkv, h16* __restrict__ Wo, h16x4* __restrict__ xb) {
  __shared__ int sfl;
  if (threadIdx.x == 0) {
    int ok = 1;
    const int* wi = (const int*)wq;
    for (int i = 0; i < 64; ++i) {
      int v = wi[i];
      if (v < -128 || v > 127) ok = 0;
    }
    sfl = ok;
  }
  __syncthreads();
  const int fl = sfl;
  int u = blockIdx.x * 256 + threadIdx.x;
  if (u < U_WQ) { dq_unit(wq, sq, Wqkv, u, fl); return; }
  u -= U_WQ;
  if (u < U_WK) { dq_unit(wk, sk, Wqkv + 16777216, u, fl); return; }
  u -= U_WK;
  if (u < U_WV) { dq_unit(wv, sv, Wqkv + 20971520, u, fl); return; }
  u -= U_WV;
  if (u < U_WO) { dq_unit(wo, so, Wo, u, fl); return; }
  u -= U_WO;
  {
    float4 v = x[u];
    h16x4 o;
    o.x = (h16)v.x; o.y = (h16)v.y; o.z = (h16)v.z; o.w = (h16)v.w;
    xb[u] = o;
  }
}

// ---------- legacy 128-tile GEMM: C[M,N] = A[M,K] @ B[N,K]^T (used for O-proj) ----------
template <typename OutT, int NT, int MODE>
__global__ __launch_bounds__(256) void gemm_bt(
    const h16* __restrict__ A, const h16* __restrict__ B,
    OutT* __restrict__ C, int M, int N, int K,
    const float* __restrict__ cosb, const float* __restrict__ sinb,
    h16* __restrict__ vt) {
  constexpr int BN = NT * 32;
  constexpr int SAB = 128 * 64 + BN * 64;                 // staging h16 count
  constexpr int SSZ = (MODE == 1 && 128 * 136 > SAB) ? 128 * 136 : SAB;
  __shared__ __attribute__((aligned(16))) h16 SMEM[SSZ];
  h16* As = SMEM;
  h16* Bs = SMEM + 128 * 64;
  h16* T  = SMEM;                                          // alias, used after K-loop

  const int tid  = threadIdx.x;
  const int wv   = tid >> 6, lane = tid & 63;
  const int wr   = wv >> 1,  wc   = wv & 1;
  const int quad = lane >> 4, l15 = lane & 15;
  const int m0 = blockIdx.y * 128, n0 = blockIdx.x * BN;

  f32x4 acc[4][NT];
#pragma unroll
  for (int i = 0; i < 4; ++i)
#pragma unroll
    for (int j = 0; j < NT; ++j) acc[i][j] = (f32x4){0.f, 0.f, 0.f, 0.f};

  const h16* Ab = A + (size_t)m0 * K;
  const h16* Bb = B + (size_t)n0 * K;

  for (int k0 = 0; k0 < K; k0 += 64) {
    __syncthreads();
#pragma unroll
    for (int i = 0; i < 4; ++i) {
      int c = i * 256 + tid;
      int row = c >> 3, cs = c & 7, g = cs ^ (row & 7);
      gload_lds16(Ab + (size_t)row * K + k0 + g * 8, (char*)As + c * 16);
    }
#pragma unroll
    for (int i = 0; i < NT; ++i) {
      int c = i * 256 + tid;
      int row = c >> 3, cs = c & 7, g = cs ^ (row & 7);
      gload_lds16(Bb + (size_t)row * K + k0 + g * 8, (char*)Bs + c * 16);
    }
    __syncthreads();

#pragma unroll
    for (int ks = 0; ks < 2; ++ks) {
      h16x8 af[4], bfr[NT];
#pragma unroll
      for (int mt = 0; mt < 4; ++mt) {
        int row = wr * 64 + mt * 16 + l15;
        af[mt] = *(const h16x8*)&As[row * 64 + (((ks * 4 + quad) ^ (row & 7)) * 8)];
      }
#pragma unroll
      for (int nt = 0; nt < NT; ++nt) {
        int row = wc * (NT * 16) + nt * 16 + l15;
        bfr[nt] = *(const h16x8*)&Bs[row * 64 + (((ks * 4 + quad) ^ (row & 7)) * 8)];
      }
#pragma unroll
      for (int mt = 0; mt < 4; ++mt)
#pragma unroll
        for (int nt = 0; nt < NT; ++nt)
          acc[mt][nt] = __builtin_amdgcn_mfma_f32_16x16x32_f16(af[mt], bfr[nt], acc[mt][nt], 0, 0, 0);
    }
  }

  if (MODE == 1) {
    if (n0 < 5120) {
      __syncthreads();
#pragma unroll
      for (int mt = 0; mt < 4; ++mt)
#pragma unroll
        for (int nt = 0; nt < NT; ++nt)
#pragma unroll
          for (int r = 0; r < 4; ++r)
            T[(wr * 64 + mt * 16 + quad * 4 + r) * 136 + wc * 64 + nt * 16 + l15] =
                (h16)acc[mt][nt][r];
      __syncthreads();
      const int row = tid >> 1, half = tid & 1;
      const size_t gs = (size_t)(m0 + row);
#pragma unroll
      for (int i = 0; i < 8; ++i) {
        int c0 = half * 32 + i * 4;            // d in [0,64)
        h16x4 a = *(const h16x4*)&T[row * 136 + c0];
        h16x4 b = *(const h16x4*)&T[row * 136 + c0 + 64];
        float4 cc = *(const float4*)(cosb + gs * 64 + c0);
        float4 ss = *(const float4*)(sinb + gs * 64 + c0);
        h16x4 oa, ob;
        oa.x = (h16)((float)a.x * cc.x - (float)b.x * ss.x);
        oa.y = (h16)((float)a.y * cc.y - (float)b.y * ss.y);
        oa.z = (h16)((float)a.z * cc.z - (float)b.z * ss.z);
        oa.w = (h16)((float)a.w * cc.w - (float)b.w * ss.w);
        ob.x = (h16)((float)b.x * cc.x + (float)a.x * ss.x);
        ob.y = (h16)((float)b.y * cc.y + (float)a.y * ss.y);
        ob.z = (h16)((float)b.z * cc.z + (float)a.z * ss.z);
        ob.w = (h16)((float)b.w * cc.w + (float)a.w * ss.w);
        *(h16x4*)((h16*)C + gs * N + n0 + c0)      = oa;
        *(h16x4*)((h16*)C + gs * N + n0 + c0 + 64) = ob;
      }
    } else {
      const int kvh = (n0 - 5120) >> 7;
      h16* vbase = vt + (size_t)kvh * HD * SEQ;
#pragma unroll
      for (int mt = 0; mt < 4; ++mt)
#pragma unroll
        for (int nt = 0; nt < NT; ++nt) {
          int d = wc * 64 + nt * 16 + l15;
          int s = m0 + wr * 64 + mt * 16 + quad * 4;
          h16x4 vvv;
#pragma unroll
          for (int r = 0; r < 4; ++r) vvv[r] = (h16)acc[mt][nt][r];
          *(h16x4*)(vbase + (size_t)d * SEQ + s) = vvv;
        }
    }
    return;
  }

#pragma unroll
  for (int mt = 0; mt < 4; ++mt)
#pragma unroll
    for (int nt = 0; nt < NT; ++nt)
#pragma unroll
      for (int r = 0; r < 4; ++r) {
        int row = m0 + wr * 64 + mt * 16 + quad * 4 + r;
        int col = n0 + wc * (NT * 16) + nt * 16 + l15;
        C[(size_t)row * N + col] = (OutT)acc[mt][nt][r];
      }
}

// ---------- 256x256 8-phase GEMM (T2+T3+T4+T5), fused RoPE / V-transpose ----------
// C[M,N] = A[M,K] @ B[N,K]^T.  8 waves (2M x 4N), BK=64, 2-deep LDS buffers.
// LDS: 2 bufs x 4 slots x (128x64 h16) = 128 KiB.  Slot order = death order:
//   slot0 = A rows [0,128)    (last ds_read phase 1 of its K-tile)
//   slot1 = B rows [128,256)  (last read phase 2)
//   slot2 = A rows [128,256)  (last read phase 3)
//   slot3 = B rows [0,128)    (last read phase 4)
// Quadrant walk per K-tile: (A0,B0) (A0,B1) (A1,B1) (A1,B0) — A frags reused
// ph1->2, B frags reused ph2->3 (12/4/8/4 ds_reads per phase).
// Stage schedule: phase p stages half-tile h(8t+6+p); its slot's last ds_read
// drained at phase p-1's end-barrier.  vmcnt(6) (=2 loads x 3 half-tiles in
// flight) only at phases 4 and 8; never vmcnt(0) inside the loop.
__global__ __launch_bounds__(512, 2) void gemm256_qkv(
    const h16* __restrict__ A, const h16* __restrict__ B, h16* __restrict__ C,
    int M, int N, int K,
    const float* __restrict__ cosb, const float* __restrict__ sinb,
    h16* __restrict__ vt) {
  __shared__ __attribute__((aligned(16))) h16 SM[65536];
  h16* T = SM;   // alias for RoPE epilogue

  const int tid  = threadIdx.x;
  const int w    = tid >> 6, lane = tid & 63;
  const int wr   = w >> 2, wc = w & 3;
  const int quad = lane >> 4, l15 = lane & 15;
  const int axr  = l15 & 7;
  const int m0 = blockIdx.y * 256, n0 = blockIdx.x * 256;

  const h16* Ab = A + (size_t)m0 * K;
  const h16* Bb = B + (size_t)n0 * K;
  const int srow = tid >> 3;                       // stage row within half (0..63)
  const int sg8  = ((tid & 7) ^ (srow & 7)) * 8;   // pre-swizzled global k-chunk

  f32x4 acc[2][2][4][2];
#pragma unroll
  for (int a = 0; a < 2; ++a)
#pragma unroll
    for (int b = 0; b < 2; ++b)
#pragma unroll
      for (int mt = 0; mt < 4; ++mt)
#pragma unroll
        for (int nt = 0; nt < 2; ++nt) acc[a][b][mt][nt] = (f32x4){0.f, 0.f, 0.f, 0.f};

  h16x8 af[4][2], bf[2][2];

#define STG(sl_, tile_) do {                                                        \
    const h16* g_ = ((sl_) == 0) ? Ab : ((sl_) == 1) ? (Bb + (size_t)128 * K)       \
                  : ((sl_) == 2) ? (Ab + (size_t)128 * K) : Bb;                     \
    char* d_ = (char*)(SM + (((tile_) & 1) ? 32768 : 0) + (sl_) * 8192);            \
    const int kk_ = (tile_) * 64;                                                   \
    gload_lds16(g_ + (size_t)srow * K + kk_ + sg8, d_ + tid * 16);                  \
    gload_lds16(g_ + (size_t)(srow + 64) * K + kk_ + sg8, d_ + (512 + tid) * 16);   \
  } while (0)

#define LDA_(tile_, a_) do {                                                        \
    const h16* s_ = SM + (((tile_) & 1) ? 32768 : 0) + ((a_) ? 2 : 0) * 8192;       \
    _Pragma("unroll") for (int mt = 0; mt < 4; ++mt)                                \
    _Pragma("unroll") for (int ks = 0; ks < 2; ++ks)                                \
      af[mt][ks] = *(const h16x8*)&s_[(wr * 64 + mt * 16 + l15) * 64 +              \
                                      (((ks * 4 + quad) ^ axr) * 8)];               \
  } while (0)

#define LDB_(tile_, b_) do {                                                        \
    const h16* s_ = SM + (((tile_) & 1) ? 32768 : 0) + ((b_) ? 1 : 3) * 8192;       \
    _Pragma("unroll") for (int nt = 0; nt < 2; ++nt)                                \
    _Pragma("unroll") for (int ks = 0; ks < 2; ++ks)                                \
      bf[nt][ks] = *(const h16x8*)&s_[(wc * 32 + nt * 16 + l15) * 64 +              \
                                      (((ks * 4 + quad) ^ axr) * 8)];               \
  } while (0)

#define MMA_(a_, b_) do {                                                           \
    __builtin_amdgcn_s_setprio(1);                                                  \
    _Pragma("unroll") for (int mt = 0; mt < 4; ++mt)                                \
    _Pragma("unroll") for (int nt = 0; nt < 2; ++nt)                                \
    _Pragma("unroll") for (int ks = 0; ks < 2; ++ks)                                \
      acc[a_][b_][mt][nt] = __builtin_amdgcn_mfma_f32_16x16x32_f16(                 \
          af[mt][ks], bf[nt][ks], acc[a_][b_][mt][nt], 0, 0, 0);                    \
    __builtin_amdgcn_s_setprio(0);                                                  \
  } while (0)

#define CFENCE asm volatile("" ::: "memory")
#define BARX do { CFENCE; __builtin_amdgcn_s_barrier(); CFENCE; } while (0)
#define LG0 do { asm volatile("s_waitcnt lgkmcnt(0)" ::: "memory");                 \
                 __builtin_amdgcn_sched_barrier(0); } while (0)
#define VM6 asm volatile("s_waitcnt vmcnt(6)" ::: "memory")
#define VM0 asm volatile("s_waitcnt vmcnt(0)" ::: "memory")

  const int NTILE = K >> 6;        // 64
  const int NIT   = NTILE >> 1;    // 32

  // prologue: 7 half-tiles in flight, wait for K-tile 0 (oldest 4)
  STG(0, 0); STG(1, 0); STG(2, 0); STG(3, 0);
  STG(0, 1); STG(1, 1); STG(2, 1);
  VM6;
  BARX;

  for (int t = 0; t < NIT; ++t) {
    const int t0 = 2 * t, t1 = 2 * t + 1;
    const int t2 = (2 * t + 2 < NTILE) ? 2 * t + 2 : NTILE - 1;   // tail clamp:
    const int t3 = (2 * t + 3 < NTILE) ? 2 * t + 3 : NTILE - 1;   // benign same-data restage
    // ---- K-tile t0 ----
    LDA_(t0, 0); LDB_(t0, 0); STG(3, t1);
    BARX; LG0; MMA_(0, 0); BARX;
    LDB_(t0, 1); STG(0, t2);
    BARX; LG0; MMA_(0, 1); BARX;
    LDA_(t0, 1); STG(1, t2);
    BARX; LG0; MMA_(1, 1); BARX;
    LDB_(t0, 0); STG(2, t2);
    BARX; LG0; MMA_(1, 0); VM6; BARX;
    // ---- K-tile t1 ----
    LDA_(t1, 0); LDB_(t1, 0); STG(3, t2);
    BARX; LG0; MMA_(0, 0); BARX;
    LDB_(t1, 1); STG(0, t3);
    BARX; LG0; MMA_(0, 1); BARX;
    LDA_(t1, 1); STG(1, t3);
    BARX; LG0; MMA_(1, 1); BARX;
    LDB_(t1, 0); STG(2, t3);
    BARX; LG0; MMA_(1, 0); VM6; BARX;
  }

  // drain tail prefetches before reusing LDS / exiting
  VM0;
  BARX;

  if (n0 < 5120) {
    // q/k block: two heads per block; per head: acc -> LDS (stride 136) -> RoPE -> store
#pragma unroll
    for (int hh = 0; hh < 2; ++hh) {
      if (hh) __syncthreads();
#pragma unroll
      for (int a = 0; a < 2; ++a)
#pragma unroll
        for (int mt = 0; mt < 4; ++mt)
#pragma unroll
          for (int nt = 0; nt < 2; ++nt)
#pragma unroll
            for (int r = 0; r < 4; ++r)
              T[(a * 128 + wr * 64 + mt * 16 + quad * 4 + r) * 136 +
                wc * 32 + nt * 16 + l15] = (h16)acc[a][hh][mt][nt][r];
      __syncthreads();
      const int row = tid >> 1, half = tid & 1;
      const size_t gs = (size_t)(m0 + row);
#pragma unroll
      for (int i = 0; i < 8; ++i) {
        int c0 = half * 32 + i * 4;            // d in [0,64)
        h16x4 a4 = *(const h16x4*)&T[row * 136 + c0];
        h16x4 b4 = *(const h16x4*)&T[row * 136 + c0 + 64];
        float4 cc = *(const float4*)(cosb + gs * 64 + c0);
        float4 ss = *(const float4*)(sinb + gs * 64 + c0);
        h16x4 oa, ob;
        oa.x = (h16)((float)a4.x * cc.x - (float)b4.x * ss.x);
        oa.y = (h16)((float)a4.y * cc.y - (float)b4.y * ss.y);
        oa.z = (h16)((float)a4.z * cc.z - (float)b4.z * ss.z);
        oa.w = (h16)((float)a4.w * cc.w - (float)b4.w * ss.w);
        ob.x = (h16)((float)b4.x * cc.x + (float)a4.x * ss.x);
        ob.y = (h16)((float)b4.y * cc.y + (float)a4.y * ss.y);
        ob.z = (h16)((float)b4.z * cc.z + (float)a4.z * ss.z);
        ob.w = (h16)((float)b4.w * cc.w + (float)a4.w * ss.w);
        *(h16x4*)(C + gs * N + n0 + hh * 128 + c0)      = oa;
        *(h16x4*)(C + gs * N + n0 + hh * 128 + c0 + 64) = ob;
      }
    }
  } else {
    // v block (2 kv-heads): direct register transpose into vt[kv][d][s]
    const int kvb = (n0 - 5120) >> 7;
#pragma unroll
    for (int a = 0; a < 2; ++a)
#pragma unroll
      for (int b = 0; b < 2; ++b)
#pragma unroll
        for (int mt = 0; mt < 4; ++mt)
#pragma unroll
          for (int nt = 0; nt < 2; ++nt) {
            int d = wc * 32 + nt * 16 + l15;
            int s = m0 + a * 128 + wr * 64 + mt * 16 + quad * 4;
            h16x4 vvv;
#pragma unroll
            for (int r = 0; r < 4; ++r) vvv[r] = (h16)acc[a][b][mt][nt][r];
            *(h16x4*)(vt + (size_t)(kvb + b) * HD * SEQ + (size_t)d * SEQ + s) = vvv;
          }
  }
#undef STG
#undef LDA_
#undef LDB_
#undef MMA_
#undef CFENCE
#undef BARX
#undef LG0
#undef VM6
#undef VM0
}

// ---------- flash attention: block = (h, y), 128 q-rows, 4 waves x 32 rows, BK=64 ----------
__global__ __launch_bounds__(256, 2) void flash_attn(
    const h16* __restrict__ qkv, const h16* __restrict__ vt, h16* __restrict__ o_out) {
  __shared__ __attribute__((aligned(16))) h16 Ks[64 * 128];
  __shared__ __attribute__((aligned(16))) h16 Vts[128 * 64];
  __shared__ __attribute__((aligned(16))) h16 Ps[4][32 * 72];

  const int tid  = threadIdx.x;
  const int w    = tid >> 6, lane = tid & 63;
  const int quad = lane >> 4, l15 = lane & 15;
  const int h    = blockIdx.x;
  const int y    = blockIdx.y;
  const int qt   = (y < 8) ? (15 - y) : (y - 8);   // balanced heavy/light pairing
  const int kv   = h >> 2;
  const int rowq = qt * 128 + w * 32;
  const h16* vtg = vt + (size_t)kv * HD * SEQ;

  h16x8 qf[2][4];
#pragma unroll
  for (int mt = 0; mt < 2; ++mt) {
    const h16* qrow = qkv + (size_t)(rowq + mt * 16 + l15) * QKVD + h * 128;
#pragma unroll
    for (int ks = 0; ks < 4; ++ks)
      qf[mt][ks] = *(const h16x8*)(qrow + ks * 32 + quad * 8);
  }

  f32x4 o[2][8];
#pragma unroll
  for (int mt = 0; mt < 2; ++mt)
#pragma unroll
    for (int i = 0; i < 8; ++i) o[mt][i] = (f32x4){0.f, 0.f, 0.f, 0.f};
  float mrow[2][4], lrow[2][4];
#pragma unroll
  for (int mt = 0; mt < 2; ++mt)
#pragma unroll
    for (int r = 0; r < 4; ++r) { mrow[mt][r] = -3e30f; lrow[mt][r] = 0.f; }
  h16* Psw = Ps[w];

  const int nkt = 2 * qt + 2;
  for (int kt = 0; kt < nkt; ++kt) {
    const int k0 = kt * 64;
    __syncthreads();
#pragma unroll
    for (int i = 0; i < 4; ++i) {
      int c = i * 256 + tid;
      int key = c >> 4, d8s = c & 15;
      gload_lds16(qkv + (size_t)(k0 + key) * QKVD + 4096 + kv * 128 + (d8s ^ (key & 15)) * 8,
                  (char*)Ks + c * 16);
    }
#pragma unroll
    for (int i = 0; i < 4; ++i) {
      int c = i * 256 + tid;
      int d = c >> 3, p = c & 7;
      gload_lds16(vtg + (size_t)d * SEQ + k0 + (p ^ (d & 7)) * 8,
                  (char*)Vts + c * 16);
    }
    __syncthreads();

    if (k0 <= rowq + 31) {
      const float sscale = 0.08838834764831845f;
      float alpha[2][4];
      f32x4 s2[2][4];
#pragma unroll
      for (int nt = 0; nt < 4; ++nt) {
        int key = nt * 16 + l15;
        f32x4 a0 = (f32x4){0.f, 0.f, 0.f, 0.f};
        f32x4 a1 = (f32x4){0.f, 0.f, 0.f, 0.f};
#pragma unroll
        for (int ks = 0; ks < 4; ++ks) {
          int d8 = ks * 4 + quad;
          h16x8 kf = *(const h16x8*)&Ks[key * 128 + ((d8 ^ (key & 15)) * 8)];
          a0 = __builtin_amdgcn_mfma_f32_16x16x32_f16(qf[0][ks], kf, a0, 0, 0, 0);
          a1 = __builtin_amdgcn_mfma_f32_16x16x32_f16(qf[1][ks], kf, a1, 0, 0, 0);
        }
        s2[0][nt] = a0;
        s2[1][nt] = a1;
      }
#pragma unroll
      for (int mt = 0; mt < 2; ++mt) {
#pragma unroll
        for (int r = 0; r < 4; ++r) {
          int rowg = rowq + mt * 16 + quad * 4 + r;
          float pv[4];
          float tm = -3e30f;
#pragma unroll
          for (int nt = 0; nt < 4; ++nt) {
            float v = s2[mt][nt][r] * sscale;
            if (k0 + nt * 16 + l15 > rowg) v = -3e30f;
            pv[nt] = v;
            tm = fmaxf(tm, v);
          }
          tm = red16_max(tm);
          float mnew = fmaxf(mrow[mt][r], tm);
          float a = __expf(mrow[mt][r] - mnew);
          mrow[mt][r] = mnew;
          alpha[mt][r] = a;
          float ps = 0.f;
#pragma unroll
          for (int nt = 0; nt < 4; ++nt) {
            float e = __expf(pv[nt] - mnew);
            ps += e;
            Psw[(mt * 16 + quad * 4 + r) * 72 + nt * 16 + l15] = (h16)e;
          }
          ps = red16_sum(ps);
          lrow[mt][r] = lrow[mt][r] * a + ps;
        }
      }
#pragma unroll
      for (int mt = 0; mt < 2; ++mt)
#pragma unroll
        for (int on = 0; on < 8; ++on) {
          o[mt][on][0] *= alpha[mt][0]; o[mt][on][1] *= alpha[mt][1];
          o[mt][on][2] *= alpha[mt][2]; o[mt][on][3] *= alpha[mt][3];
        }
      asm volatile("s_waitcnt lgkmcnt(0)" ::: "memory");
#pragma unroll
      for (int ks = 0; ks < 2; ++ks) {
        h16x8 pf0 = *(const h16x8*)&Psw[(0  + l15) * 72 + ks * 32 + quad * 8];
        h16x8 pf1 = *(const h16x8*)&Psw[(16 + l15) * 72 + ks * 32 + quad * 8];
        int k8 = ks * 4 + quad;
#pragma unroll
        for (int on = 0; on < 8; ++on) {
          int d = on * 16 + l15;
          h16x8 vf = *(const h16x8*)&Vts[d * 64 + ((k8 ^ (d & 7)) * 8)];
          o[0][on] = __builtin_amdgcn_mfma_f32_16x16x32_f16(pf0, vf, o[0][on], 0, 0, 0);
          o[1][on] = __builtin_amdgcn_mfma_f32_16x16x32_f16(pf1, vf, o[1][on], 0, 0, 0);
        }
      }
    }
  }
#pragma unroll
  for (int mt = 0; mt < 2; ++mt) {
    float linv[4];
#pragma unroll
    for (int r = 0; r < 4; ++r) linv[r] = 1.0f / lrow[mt][r];
#pragma unroll
    for (int on = 0; on < 8; ++on)
#pragma unroll
      for (int r = 0; r < 4; ++r) {
        int row = rowq + mt * 16 + quad * 4 + r;
        int col = h * 128 + on * 16 + l15;
        o_out[(size_t)row * DIMX + col] = (h16)(o[mt][on][r] * linv[r]);
      }
  }
}

extern "C" void kernel_launch(void* const* d_in, const int* in_sizes, int n_in,
                              void* d_out, int out_size, void* d_ws, size_t ws_size,
                              hipStream_t stream) {
  const float* x    = (const float*)d_in[0];
  const void*  wq   = d_in[1];
  const float* sq   = (const float*)d_in[2];
  const void*  wk   = d_in[3];
  const float* sk   = (const float*)d_in[4];
  const void*  wv   = d_in[5];
  const float* sv   = (const float*)d_in[6];
  const void*  wo   = d_in[7];
  const float* so   = (const float*)d_in[8];
  const float* cosb = (const float*)d_in[9];
  const float* sinb = (const float*)d_in[10];
  float* out = (float*)d_out;

  char* ws = (char*)d_ws;
  h16* Wqkv = (h16*)ws;                      // 6144*4096 h16 = 50331648 B
  h16* Wo   = (h16*)(ws + 50331648);         // 4096*4096 h16 = 33554432 B
  h16* xb   = (h16*)(ws + 83886080);         // x as h16; later attn_out
  h16* qkv  = (h16*)(ws + 100663296);        // 2048*6144 h16
  h16* vt   = (h16*)d_out;                   // vt scratch lives in d_out (dead until O-proj)

  // fused dequant (wq,wk,wv,wo) + cast(x)
  prep_all<<<28672, 256, 0, stream>>>(wq, sq, wk, sk, wv, sv, wo, so,
                                      (const float4*)x, Wqkv, Wo, (h16x4*)xb);

  // qkv = x @ Wqkv^T, 256x256 8-phase schedule, fused RoPE (q,k) + V-transpose
  gemm256_qkv<<<dim3(24, 8), 512, 0, stream>>>(
      xb, Wqkv, qkv, SEQ, QKVD, DIMX, cosb, sinb, vt);

  // flash attention -> attn_out (reuse xb region)
  flash_attn<<<dim3(32, 16), 256, 0, stream>>>(qkv, vt, xb);

  // out = attn_out @ Wo^T  (BN=128 tile -> 512 blocks, 2/CU)
  gemm_bt<float, 4, 0><<<dim3(32, 16), 256, 0, stream>>>(
      xb, Wo, out, SEQ, DIMX, DIMX, cosb, sinb, vt);
}

// Round 2
// 457.798 us; speedup vs baseline: 1.0710x; 1.0166x over previous
//
#include <hip/hip_runtime.h>
#include <stdint.h>

// Problem constants (fixed shapes)
#define DIMX 4096
#define NH   32
#define NKV  8
#define HD   128
#define SEQ  2048
#define QKVD 6144   // 4096 q + 1024 k + 1024 v

typedef _Float16 h16;
typedef __attribute__((ext_vector_type(8))) _Float16 h16x8;
typedef __attribute__((ext_vector_type(4))) _Float16 h16x4;
typedef __attribute__((ext_vector_type(4))) float   f32x4;

__device__ __forceinline__ void gload_lds16(const void* g, void* l) {
  __builtin_amdgcn_global_load_lds(
      (const __attribute__((address_space(1))) void*)g,
      (__attribute__((address_space(3))) void*)l, 16, 0, 0);
}

// ---- 16-lane reductions on the VALU via DPP reversal butterflies (no LDS pipe) ----
template <int CTRL>
__device__ __forceinline__ float dpp_mv(float x) {
  int y = __builtin_amdgcn_mov_dpp(__builtin_bit_cast(int, x), CTRL, 0xF, 0xF, true);
  return __builtin_bit_cast(float, y);
}
__device__ __forceinline__ float red16_max(float x) {
  x = fmaxf(x, dpp_mv<0xB1>(x));   // rev2
  x = fmaxf(x, dpp_mv<0x1B>(x));   // rev4
  x = fmaxf(x, dpp_mv<0x141>(x));  // rev8
  x = fmaxf(x, dpp_mv<0x140>(x));  // rev16
  return x;
}
__device__ __forceinline__ float red16_sum(float x) {
  x += dpp_mv<0xB1>(x);
  x += dpp_mv<0x1B>(x);
  x += dpp_mv<0x141>(x);
  x += dpp_mv<0x140>(x);
  return x;
}

// ---------- fused dequant (all 4 weights) + x cast ----------
// PERM=1 (q/k weights): permute out-feature rows so RoPE pairs (d, d+64) become
// adjacent interleaved columns (d' = 2*(d&63) | (d>>6)).  QK^T dot products are
// invariant under a shared per-head permutation of d, so flash_attn is unchanged;
// only the RoPE epilogue (pairing now lane^1) and cos/sin indexing (j=(col&127)>>1)
// need to know.
template <int PERM>
__device__ __forceinline__ void dq_unit(const void* __restrict__ w, const float* __restrict__ sc,
                                        h16* __restrict__ out, int u, int flag) {
  uint32_t b4;
  if (flag) {
    const int4 t = *(const int4*)((const int*)w + 4 * u);
    b4 = (uint32_t)(t.x & 0xFF) | ((uint32_t)(t.y & 0xFF) << 8) |
         ((uint32_t)(t.z & 0xFF) << 16) | ((uint32_t)(t.w & 0xFF) << 24);
  } else {
    b4 = ((const uint32_t*)w)[u];
  }
  int r = u >> 4;
  int p = (u & 15) * 4;
  float shi = sc[2 * r], slo = sc[2 * r + 1];
  h16x4 hi, lo;
#pragma unroll
  for (int j = 0; j < 4; ++j) {
    int by = (int)((b4 >> (8 * j)) & 0xFF);
    int hn = (by << 24) >> 28;
    int ln = (by << 28) >> 28;
    hi[j] = (h16)((float)hn * shi);
    lo[j] = (h16)((float)ln * slo);
  }
  size_t base;
  if (PERM) {
    int row  = r >> 5;                                           // out-feature row
    int rowp = (row & ~127) | (((row & 63) << 1) | ((row >> 6) & 1));
    base = ((size_t)rowp << 12) + (size_t)((r & 31) << 7);
  } else {
    base = (size_t)r << 7;
  }
  *(h16x4*)(out + base + p)      = hi;
  *(h16x4*)(out + base + 64 + p) = lo;
}

#define U_WQ 2097152
#define U_WK 524288
#define U_WV 524288
#define U_WO 2097152

__global__ __launch_bounds__(256) void prep_all(
    const void* __restrict__ wq, const float* __restrict__ sq,
    const void* __restrict__ wk, const float* __restrict__ sk,
    const void* __restrict__ wv, const float* __restrict__ sv,
    const void* __restrict__ wo, const float* __restrict__ so,
    const float4* __restrict__ x,
    h16* __restrict__ Wqkv, h16* __restrict__ Wo, h16x4* __restrict__ xb) {
  __shared__ int sfl;
  if (threadIdx.x == 0) {
    int ok = 1;
    const int* wi = (const int*)wq;
    for (int i = 0; i < 64; ++i) {
      int v = wi[i];
      if (v < -128 || v > 127) ok = 0;
    }
    sfl = ok;
  }
  __syncthreads();
  const int fl = sfl;
  int u = blockIdx.x * 256 + threadIdx.x;
  if (u < U_WQ) { dq_unit<1>(wq, sq, Wqkv, u, fl); return; }
  u -= U_WQ;
  if (u < U_WK) { dq_unit<1>(wk, sk, Wqkv + 16777216, u, fl); return; }
  u -= U_WK;
  if (u < U_WV) { dq_unit<0>(wv, sv, Wqkv + 20971520, u, fl); return; }
  u -= U_WV;
  if (u < U_WO) { dq_unit<0>(wo, so, Wo, u, fl); return; }
  u -= U_WO;
  {
    float4 v = x[u];
    h16x4 o;
    o.x = (h16)v.x; o.y = (h16)v.y; o.z = (h16)v.z; o.w = (h16)v.w;
    xb[u] = o;
  }
}

// ---------- legacy 128-tile GEMM: C[M,N] = A[M,K] @ B[N,K]^T (used for O-proj) ----------
template <typename OutT, int NT, int MODE>
__global__ __launch_bounds__(256) void gemm_bt(
    const h16* __restrict__ A, const h16* __restrict__ B,
    OutT* __restrict__ C, int M, int N, int K,
    const float* __restrict__ cosb, const float* __restrict__ sinb,
    h16* __restrict__ vt) {
  constexpr int BN = NT * 32;
  constexpr int SSZ = 128 * 64 + BN * 64;
  __shared__ __attribute__((aligned(16))) h16 SMEM[SSZ];
  h16* As = SMEM;
  h16* Bs = SMEM + 128 * 64;

  const int tid  = threadIdx.x;
  const int wv   = tid >> 6, lane = tid & 63;
  const int wr   = wv >> 1,  wc   = wv & 1;
  const int quad = lane >> 4, l15 = lane & 15;
  const int m0 = blockIdx.y * 128, n0 = blockIdx.x * BN;

  f32x4 acc[4][NT];
#pragma unroll
  for (int i = 0; i < 4; ++i)
#pragma unroll
    for (int j = 0; j < NT; ++j) acc[i][j] = (f32x4){0.f, 0.f, 0.f, 0.f};

  const h16* Ab = A + (size_t)m0 * K;
  const h16* Bb = B + (size_t)n0 * K;

  for (int k0 = 0; k0 < K; k0 += 64) {
    __syncthreads();
#pragma unroll
    for (int i = 0; i < 4; ++i) {
      int c = i * 256 + tid;
      int row = c >> 3, cs = c & 7, g = cs ^ (row & 7);
      gload_lds16(Ab + (size_t)row * K + k0 + g * 8, (char*)As + c * 16);
    }
#pragma unroll
    for (int i = 0; i < NT; ++i) {
      int c = i * 256 + tid;
      int row = c >> 3, cs = c & 7, g = cs ^ (row & 7);
      gload_lds16(Bb + (size_t)row * K + k0 + g * 8, (char*)Bs + c * 16);
    }
    __syncthreads();

#pragma unroll
    for (int ks = 0; ks < 2; ++ks) {
      h16x8 af[4], bfr[NT];
#pragma unroll
      for (int mt = 0; mt < 4; ++mt) {
        int row = wr * 64 + mt * 16 + l15;
        af[mt] = *(const h16x8*)&As[row * 64 + (((ks * 4 + quad) ^ (row & 7)) * 8)];
      }
#pragma unroll
      for (int nt = 0; nt < NT; ++nt) {
        int row = wc * (NT * 16) + nt * 16 + l15;
        bfr[nt] = *(const h16x8*)&Bs[row * 64 + (((ks * 4 + quad) ^ (row & 7)) * 8)];
      }
#pragma unroll
      for (int mt = 0; mt < 4; ++mt)
#pragma unroll
        for (int nt = 0; nt < NT; ++nt)
          acc[mt][nt] = __builtin_amdgcn_mfma_f32_16x16x32_f16(af[mt], bfr[nt], acc[mt][nt], 0, 0, 0);
    }
  }

#pragma unroll
  for (int mt = 0; mt < 4; ++mt)
#pragma unroll
    for (int nt = 0; nt < NT; ++nt)
#pragma unroll
      for (int r = 0; r < 4; ++r) {
        int row = m0 + wr * 64 + mt * 16 + quad * 4 + r;
        int col = n0 + wc * (NT * 16) + nt * 16 + l15;
        C[(size_t)row * N + col] = (OutT)acc[mt][nt][r];
      }
}

// ---------- 256x192 8-phase QKV GEMM, 256 blocks (full CU coverage) ----------
// C[2048,6144] = A[2048,4096] @ B[6144,4096]^T.  8 waves as 4M x 2N; per-wave
// 64 x 96; quadrants a (32-row halves) x b (96-col halves); 12 MFMA/phase.
// LDS: 2 bufs x 7 slots x 8 KB = 112 KB.  Slots: A0..A3 (64 rows each),
// B0..B2 (64 rows each, contiguous 192-row region).  One gload_lds per stage.
// bf holds BOTH b-halves in regs -> no phase-4 re-read; ds_reads/phase {10,6,4,0}.
// Slot lifetimes (reads): A* ph1(a0)+ph3(a1); B0 ph1; B1 ph1+ph2; B2 ph2.
// Stage plan (tile t): ph1: A2,A3(t+1); ph2: B0(t+2); ph3: B1(t+2);
// ph4: B2,A0,A1(t+2) then vmcnt(5) [5 stages in flight after binding A3(t+1)].
// Every stage targets a slot whose last read drained >=1 barrier earlier; tail
// clamps restage identical data (benign).  RoPE epilogue is pure-register via
// interleaved-pair weight permutation (partner = lane^1 DPP swap).
__global__ __launch_bounds__(512, 2) void gemm192_qkv(
    const h16* __restrict__ A, const h16* __restrict__ B, h16* __restrict__ C,
    const float* __restrict__ cosb, const float* __restrict__ sinb,
    h16* __restrict__ vt) {
  constexpr int K = DIMX;
  __shared__ __attribute__((aligned(16))) h16 SM[57344];   // 2 x 28672

  const int tid  = threadIdx.x;
  const int w    = tid >> 6, lane = tid & 63;
  const int wr   = w >> 1, wc = w & 1;          // 4M x 2N waves
  const int quad = lane >> 4, l15 = lane & 15;
  const int m0 = blockIdx.y * 256, n0 = blockIdx.x * 192;

  const h16* Ab = A + (size_t)m0 * K;
  const h16* Bb = B + (size_t)n0 * K;
  const int srow = tid >> 3;                       // stage row within slot (0..63)
  const int sg8  = ((tid & 7) ^ (srow & 7)) * 8;   // pre-swizzled global k-chunk

  f32x4 acc[2][2][2][3];                            // [a][b][mt][nt]
#pragma unroll
  for (int a = 0; a < 2; ++a)
#pragma unroll
    for (int b = 0; b < 2; ++b)
#pragma unroll
      for (int mt = 0; mt < 2; ++mt)
#pragma unroll
        for (int nt = 0; nt < 3; ++nt) acc[a][b][mt][nt] = (f32x4){0.f, 0.f, 0.f, 0.f};

  h16x8 af[2][2];        // a-half fragments [mt][ks]
  h16x8 bf[2][3][2];     // BOTH b-halves persistent [b][nt][ks]

#define STG(sl_, tile_) do {                                                        \
    const h16* g_ = ((sl_) < 4) ? (Ab + (size_t)((sl_) * 64) * K)                   \
                                : (Bb + (size_t)(((sl_) - 4) * 64) * K);            \
    char* d_ = (char*)(SM + ((tile_) & 1) * 28672 + (sl_) * 4096);                  \
    gload_lds16(g_ + (size_t)srow * K + (tile_) * 64 + sg8, d_ + tid * 16);         \
  } while (0)

#define LDA_(tile_, a_) do {                                                        \
    const h16* s_ = SM + ((tile_) & 1) * 28672 + wr * 4096;                         \
    _Pragma("unroll") for (int mt = 0; mt < 2; ++mt)                                \
    _Pragma("unroll") for (int ks = 0; ks < 2; ++ks) {                              \
      int row_ = (a_) * 32 + mt * 16 + l15;                                         \
      af[mt][ks] = *(const h16x8*)&s_[row_ * 64 + (((ks * 4 + quad) ^ (row_ & 7)) * 8)]; \
    }                                                                               \
  } while (0)

#define LDB_(tile_, b_) do {                                                        \
    const h16* s_ = SM + ((tile_) & 1) * 28672 + 16384;                             \
    _Pragma("unroll") for (int nt = 0; nt < 3; ++nt)                                \
    _Pragma("unroll") for (int ks = 0; ks < 2; ++ks) {                              \
      int row_ = (b_) * 96 + wc * 48 + nt * 16 + l15;                               \
      bf[b_][nt][ks] = *(const h16x8*)&s_[row_ * 64 + (((ks * 4 + quad) ^ (row_ & 7)) * 8)]; \
    }                                                                               \
  } while (0)

#define MMA_(a_, b_) do {                                                           \
    __builtin_amdgcn_s_setprio(1);                                                  \
    _Pragma("unroll") for (int mt = 0; mt < 2; ++mt)                                \
    _Pragma("unroll") for (int nt = 0; nt < 3; ++nt)                                \
    _Pragma("unroll") for (int ks = 0; ks < 2; ++ks)                                \
      acc[a_][b_][mt][nt] = __builtin_amdgcn_mfma_f32_16x16x32_f16(                 \
          af[mt][ks], bf[b_][nt][ks], acc[a_][b_][mt][nt], 0, 0, 0);                \
    __builtin_amdgcn_s_setprio(0);                                                  \
  } while (0)

#define CFENCE asm volatile("" ::: "memory")
#define BARX do { CFENCE; __builtin_amdgcn_s_barrier(); CFENCE; } while (0)
#define LG0  asm volatile("s_waitcnt lgkmcnt(0)" ::: "memory")
#define LKH8 asm volatile("s_waitcnt lgkmcnt(8)" ::: "memory")
#define VM5  asm volatile("s_waitcnt vmcnt(5)" ::: "memory")
#define VM0  asm volatile("s_waitcnt vmcnt(0)" ::: "memory")

  const int NT2 = K >> 6;   // 64 K-tiles

  // prologue: tile0 complete + {B0,B1,B2,A0,A1}(1) in flight  (12 stages)
  STG(4, 0); STG(5, 0); STG(6, 0); STG(0, 0); STG(1, 0);
  STG(2, 0); STG(3, 0);
  STG(4, 1); STG(5, 1); STG(6, 1); STG(0, 1); STG(1, 1);
  VM5;          // drain 7 oldest = tile0 ready; 5 remain in flight
  BARX;

  for (int t = 0; t < NT2; ++t) {
    const int tp1 = (t + 1 < NT2) ? t + 1 : NT2 - 1;   // tail: benign same-data restage
    const int tp2 = (t + 2 < NT2) ? t + 2 : NT2 - 1;
    // ---- ph1: quadrant (a0,b0) ----
    LDA_(t, 0); LDB_(t, 0);            // 10 ds_reads
    STG(2, tp1); STG(3, tp1);          // A2,A3 for t+1 (inactive buf)
    LKH8;
    BARX; LG0; MMA_(0, 0); BARX;
    // ---- ph2: (a0,b1), af reused ----
    LDB_(t, 1);                        // 6 ds_reads
    STG(4, tp2);                       // B0 (active buf, dead after ph1)
    BARX; LG0; MMA_(0, 1); BARX;
    // ---- ph3: (a1,b1), bf[1] reused ----
    LDA_(t, 1);                        // 4 ds_reads
    STG(5, tp2);                       // B1 (dead after ph2)
    BARX; LG0; MMA_(1, 1); BARX;
    // ---- ph4: (a1,b0), all from regs ----
    STG(6, tp2); STG(0, tp2); STG(1, tp2);   // B2 (dead ph2), A0,A1 (dead ph3)
    BARX; MMA_(1, 0); VM5; BARX;
  }
  VM0;   // drain tail prefetches

  // ---------- pure-register epilogue: RoPE (interleaved pairs) or V-transpose ----------
#pragma unroll
  for (int a = 0; a < 2; ++a)
#pragma unroll
    for (int b = 0; b < 2; ++b)
#pragma unroll
      for (int mt = 0; mt < 2; ++mt)
#pragma unroll
        for (int nt = 0; nt < 3; ++nt) {
          const int cb   = n0 + b * 96 + wc * 48 + nt * 16;   // chunk base col (wave-uniform)
          const int row0 = m0 + wr * 64 + a * 32 + mt * 16 + quad * 4;
          if (cb >= 5120) {
            // V chunk: register transpose into vt[kv][d][s] (vt + dcol*SEQ + s)
            const int dcol = cb + l15 - 5120;
            h16x4 vvv;
#pragma unroll
            for (int r = 0; r < 4; ++r) vvv[r] = (h16)acc[a][b][mt][nt][r];
            *(h16x4*)(vt + (size_t)dcol * SEQ + row0) = vvv;
          } else {
            // q/k chunk: RoPE with partner = lane^1 (interleaved-pair permutation)
            const int col = cb + l15;
            const int j   = (col & 127) >> 1;
            const float sgn = (col & 1) ? 1.f : -1.f;
#pragma unroll
            for (int r = 0; r < 4; ++r) {
              float own = acc[a][b][mt][nt][r];
              float par = dpp_mv<0xB1>(own);               // quad_perm(1,0,3,2): lane^1
              float cc  = cosb[(size_t)(row0 + r) * 64 + j];
              float ss  = sinb[(size_t)(row0 + r) * 64 + j];
              C[(size_t)(row0 + r) * QKVD + col] = (h16)(own * cc + sgn * par * ss);
            }
          }
        }
#undef STG
#undef LDA_
#undef LDB_
#undef MMA_
#undef CFENCE
#undef BARX
#undef LG0
#undef LKH8
#undef VM5
#undef VM0
}

// ---------- flash attention: block = (h, y), 128 q-rows, 4 waves x 32 rows, BK=64 ----------
__global__ __launch_bounds__(256, 2) void flash_attn(
    const h16* __restrict__ qkv, const h16* __restrict__ vt, h16* __restrict__ o_out) {
  __shared__ __attribute__((aligned(16))) h16 Ks[64 * 128];
  __shared__ __attribute__((aligned(16))) h16 Vts[128 * 64];
  __shared__ __attribute__((aligned(16))) h16 Ps[4][32 * 72];

  const int tid  = threadIdx.x;
  const int w    = tid >> 6, lane = tid & 63;
  const int quad = lane >> 4, l15 = lane & 15;
  const int h    = blockIdx.x;
  const int y    = blockIdx.y;
  const int qt   = (y < 8) ? (15 - y) : (y - 8);   // balanced heavy/light pairing
  const int kv   = h >> 2;
  const int rowq = qt * 128 + w * 32;
  const h16* vtg = vt + (size_t)kv * HD * SEQ;

  h16x8 qf[2][4];
#pragma unroll
  for (int mt = 0; mt < 2; ++mt) {
    const h16* qrow = qkv + (size_t)(rowq + mt * 16 + l15) * QKVD + h * 128;
#pragma unroll
    for (int ks = 0; ks < 4; ++ks)
      qf[mt][ks] = *(const h16x8*)(qrow + ks * 32 + quad * 8);
  }

  f32x4 o[2][8];
#pragma unroll
  for (int mt = 0; mt < 2; ++mt)
#pragma unroll
    for (int i = 0; i < 8; ++i) o[mt][i] = (f32x4){0.f, 0.f, 0.f, 0.f};
  float mrow[2][4], lrow[2][4];
#pragma unroll
  for (int mt = 0; mt < 2; ++mt)
#pragma unroll
    for (int r = 0; r < 4; ++r) { mrow[mt][r] = -3e30f; lrow[mt][r] = 0.f; }
  h16* Psw = Ps[w];

  const int nkt = 2 * qt + 2;
  for (int kt = 0; kt < nkt; ++kt) {
    const int k0 = kt * 64;
    __syncthreads();
#pragma unroll
    for (int i = 0; i < 4; ++i) {
      int c = i * 256 + tid;
      int key = c >> 4, d8s = c & 15;
      gload_lds16(qkv + (size_t)(k0 + key) * QKVD + 4096 + kv * 128 + (d8s ^ (key & 15)) * 8,
                  (char*)Ks + c * 16);
    }
#pragma unroll
    for (int i = 0; i < 4; ++i) {
      int c = i * 256 + tid;
      int d = c >> 3, p = c & 7;
      gload_lds16(vtg + (size_t)d * SEQ + k0 + (p ^ (d & 7)) * 8,
                  (char*)Vts + c * 16);
    }
    __syncthreads();

    if (k0 <= rowq + 31) {
      const float sscale = 0.08838834764831845f;
      float alpha[2][4];
      f32x4 s2[2][4];
#pragma unroll
      for (int nt = 0; nt < 4; ++nt) {
        int key = nt * 16 + l15;
        f32x4 a0 = (f32x4){0.f, 0.f, 0.f, 0.f};
        f32x4 a1 = (f32x4){0.f, 0.f, 0.f, 0.f};
#pragma unroll
        for (int ks = 0; ks < 4; ++ks) {
          int d8 = ks * 4 + quad;
          h16x8 kf = *(const h16x8*)&Ks[key * 128 + ((d8 ^ (key & 15)) * 8)];
          a0 = __builtin_amdgcn_mfma_f32_16x16x32_f16(qf[0][ks], kf, a0, 0, 0, 0);
          a1 = __builtin_amdgcn_mfma_f32_16x16x32_f16(qf[1][ks], kf, a1, 0, 0, 0);
        }
        s2[0][nt] = a0;
        s2[1][nt] = a1;
      }
#pragma unroll
      for (int mt = 0; mt < 2; ++mt) {
#pragma unroll
        for (int r = 0; r < 4; ++r) {
          int rowg = rowq + mt * 16 + quad * 4 + r;
          float pv[4];
          float tm = -3e30f;
#pragma unroll
          for (int nt = 0; nt < 4; ++nt) {
            float v = s2[mt][nt][r] * sscale;
            if (k0 + nt * 16 + l15 > rowg) v = -3e30f;
            pv[nt] = v;
            tm = fmaxf(tm, v);
          }
          tm = red16_max(tm);
          float mnew = fmaxf(mrow[mt][r], tm);
          float a = __expf(mrow[mt][r] - mnew);
          mrow[mt][r] = mnew;
          alpha[mt][r] = a;
          float ps = 0.f;
#pragma unroll
          for (int nt = 0; nt < 4; ++nt) {
            float e = __expf(pv[nt] - mnew);
            ps += e;
            Psw[(mt * 16 + quad * 4 + r) * 72 + nt * 16 + l15] = (h16)e;
          }
          ps = red16_sum(ps);
          lrow[mt][r] = lrow[mt][r] * a + ps;
        }
      }
#pragma unroll
      for (int mt = 0; mt < 2; ++mt)
#pragma unroll
        for (int on = 0; on < 8; ++on) {
          o[mt][on][0] *= alpha[mt][0]; o[mt][on][1] *= alpha[mt][1];
          o[mt][on][2] *= alpha[mt][2]; o[mt][on][3] *= alpha[mt][3];
        }
      asm volatile("s_waitcnt lgkmcnt(0)" ::: "memory");
#pragma unroll
      for (int ks = 0; ks < 2; ++ks) {
        h16x8 pf0 = *(const h16x8*)&Psw[(0  + l15) * 72 + ks * 32 + quad * 8];
        h16x8 pf1 = *(const h16x8*)&Psw[(16 + l15) * 72 + ks * 32 + quad * 8];
        int k8 = ks * 4 + quad;
#pragma unroll
        for (int on = 0; on < 8; ++on) {
          int d = on * 16 + l15;
          h16x8 vf = *(const h16x8*)&Vts[d * 64 + ((k8 ^ (d & 7)) * 8)];
          o[0][on] = __builtin_amdgcn_mfma_f32_16x16x32_f16(pf0, vf, o[0][on], 0, 0, 0);
          o[1][on] = __builtin_amdgcn_mfma_f32_16x16x32_f16(pf1, vf, o[1][on], 0, 0, 0);
        }
      }
    }
  }
#pragma unroll
  for (int mt = 0; mt < 2; ++mt) {
    float linv[4];
#pragma unroll
    for (int r = 0; r < 4; ++r) linv[r] = 1.0f / lrow[mt][r];
#pragma unroll
    for (int on = 0; on < 8; ++on)
#pragma unroll
      for (int r = 0; r < 4; ++r) {
        int row = rowq + mt * 16 + quad * 4 + r;
        int col = h * 128 + on * 16 + l15;
        o_out[(size_t)row * DIMX + col] = (h16)(o[mt][on][r] * linv[r]);
      }
  }
}

extern "C" void kernel_launch(void* const* d_in, const int* in_sizes, int n_in,
                              void* d_out, int out_size, void* d_ws, size_t ws_size,
                              hipStream_t stream) {
  const float* x    = (const float*)d_in[0];
  const void*  wq   = d_in[1];
  const float* sq   = (const float*)d_in[2];
  const void*  wk   = d_in[3];
  const float* sk   = (const float*)d_in[4];
  const void*  wv   = d_in[5];
  const float* sv   = (const float*)d_in[6];
  const void*  wo   = d_in[7];
  const float* so   = (const float*)d_in[8];
  const float* cosb = (const float*)d_in[9];
  const float* sinb = (const float*)d_in[10];
  float* out = (float*)d_out;

  char* ws = (char*)d_ws;
  h16* Wqkv = (h16*)ws;                      // 6144*4096 h16 = 50331648 B
  h16* Wo   = (h16*)(ws + 50331648);         // 4096*4096 h16 = 33554432 B
  h16* xb   = (h16*)(ws + 83886080);         // x as h16; later attn_out
  h16* qkv  = (h16*)(ws + 100663296);        // 2048*6144 h16
  h16* vt   = (h16*)d_out;                   // vt scratch lives in d_out (dead until O-proj)

  // fused dequant (wq,wk: RoPE-pair-interleaved rows; wv,wo plain) + cast(x)
  prep_all<<<28672, 256, 0, stream>>>(wq, sq, wk, sk, wv, sv, wo, so,
                                      (const float4*)x, Wqkv, Wo, (h16x4*)xb);

  // qkv = x @ Wqkv^T, 256x192 8-phase schedule (256 blocks = 1/CU),
  // fused register RoPE (q,k) + direct V-transpose
  gemm192_qkv<<<dim3(32, 8), 512, 0, stream>>>(xb, Wqkv, qkv, cosb, sinb, vt);

  // flash attention -> attn_out (reuse xb region)
  flash_attn<<<dim3(32, 16), 256, 0, stream>>>(qkv, vt, xb);

  // out = attn_out @ Wo^T  (BN=128 tile -> 512 blocks, 2/CU)
  gemm_bt<float, 4, 0><<<dim3(32, 16), 256, 0, stream>>>(
      xb, Wo, out, SEQ, DIMX, DIMX, cosb, sinb, vt);
}

// Round 4
// 433.391 us; speedup vs baseline: 1.1313x; 1.0563x over previous
//
#include <hip/hip_runtime.h>
#include <stdint.h>

// Problem constants (fixed shapes)
#define DIMX 4096
#define NH   32
#define NKV  8
#define HD   128
#define SEQ  2048
#define QKVD 6144   // 4096 q + 1024 k + 1024 v

typedef _Float16 h16;
typedef __attribute__((ext_vector_type(8))) _Float16 h16x8;
typedef __attribute__((ext_vector_type(4))) _Float16 h16x4;
typedef __attribute__((ext_vector_type(4))) float   f32x4;

__device__ __forceinline__ void gload_lds16(const void* g, void* l) {
  __builtin_amdgcn_global_load_lds(
      (const __attribute__((address_space(1))) void*)g,
      (__attribute__((address_space(3))) void*)l, 16, 0, 0);
}

// ---- 16-lane reductions on the VALU via DPP reversal butterflies (no LDS pipe) ----
template <int CTRL>
__device__ __forceinline__ float dpp_mv(float x) {
  int y = __builtin_amdgcn_mov_dpp(__builtin_bit_cast(int, x), CTRL, 0xF, 0xF, true);
  return __builtin_bit_cast(float, y);
}
__device__ __forceinline__ float red16_max(float x) {
  x = fmaxf(x, dpp_mv<0xB1>(x));   // rev2
  x = fmaxf(x, dpp_mv<0x1B>(x));   // rev4
  x = fmaxf(x, dpp_mv<0x141>(x));  // rev8
  x = fmaxf(x, dpp_mv<0x140>(x));  // rev16
  return x;
}
__device__ __forceinline__ float red16_sum(float x) {
  x += dpp_mv<0xB1>(x);
  x += dpp_mv<0x1B>(x);
  x += dpp_mv<0x141>(x);
  x += dpp_mv<0x140>(x);
  return x;
}

// ---------- fused dequant (all 4 weights) + x cast ----------
// PERM=1 (q/k weights): permute out-feature rows so RoPE pairs (d, d+64) become
// adjacent interleaved columns (d' = 2*(d&63) | (d>>6)).  QK^T dot products are
// invariant under a shared per-head permutation of d, so flash_attn is unchanged;
// only the RoPE epilogue (pairing now lane^1) and cos/sin indexing (j=(col&127)>>1)
// need to know.
template <int PERM>
__device__ __forceinline__ void dq_unit(const void* __restrict__ w, const float* __restrict__ sc,
                                        h16* __restrict__ out, int u, int flag) {
  uint32_t b4;
  if (flag) {
    const int4 t = *(const int4*)((const int*)w + 4 * u);
    b4 = (uint32_t)(t.x & 0xFF) | ((uint32_t)(t.y & 0xFF) << 8) |
         ((uint32_t)(t.z & 0xFF) << 16) | ((uint32_t)(t.w & 0xFF) << 24);
  } else {
    b4 = ((const uint32_t*)w)[u];
  }
  int r = u >> 4;
  int p = (u & 15) * 4;
  float shi = sc[2 * r], slo = sc[2 * r + 1];
  h16x4 hi, lo;
#pragma unroll
  for (int j = 0; j < 4; ++j) {
    int by = (int)((b4 >> (8 * j)) & 0xFF);
    int hn = (by << 24) >> 28;
    int ln = (by << 28) >> 28;
    hi[j] = (h16)((float)hn * shi);
    lo[j] = (h16)((float)ln * slo);
  }
  size_t base;
  if (PERM) {
    int row  = r >> 5;                                           // out-feature row
    int rowp = (row & ~127) | (((row & 63) << 1) | ((row >> 6) & 1));
    base = ((size_t)rowp << 12) + (size_t)((r & 31) << 7);
  } else {
    base = (size_t)r << 7;
  }
  *(h16x4*)(out + base + p)      = hi;
  *(h16x4*)(out + base + 64 + p) = lo;
}

#define U_WQ 2097152
#define U_WK 524288
#define U_WV 524288
#define U_WO 2097152

__global__ __launch_bounds__(256) void prep_all(
    const void* __restrict__ wq, const float* __restrict__ sq,
    const void* __restrict__ wk, const float* __restrict__ sk,
    const void* __restrict__ wv, const float* __restrict__ sv,
    const void* __restrict__ wo, const float* __restrict__ so,
    const float4* __restrict__ x,
    h16* __restrict__ Wqkv, h16* __restrict__ Wo, h16x4* __restrict__ xb) {
  __shared__ int sfl;
  if (threadIdx.x == 0) {
    int ok = 1;
    const int* wi = (const int*)wq;
    for (int i = 0; i < 64; ++i) {
      int v = wi[i];
      if (v < -128 || v > 127) ok = 0;
    }
    sfl = ok;
  }
  __syncthreads();
  const int fl = sfl;
  int u = blockIdx.x * 256 + threadIdx.x;
  if (u < U_WQ) { dq_unit<1>(wq, sq, Wqkv, u, fl); return; }
  u -= U_WQ;
  if (u < U_WK) { dq_unit<1>(wk, sk, Wqkv + 16777216, u, fl); return; }
  u -= U_WK;
  if (u < U_WV) { dq_unit<0>(wv, sv, Wqkv + 20971520, u, fl); return; }
  u -= U_WV;
  if (u < U_WO) { dq_unit<0>(wo, so, Wo, u, fl); return; }
  u -= U_WO;
  {
    float4 v = x[u];
    h16x4 o;
    o.x = (h16)v.x; o.y = (h16)v.y; o.z = (h16)v.z; o.w = (h16)v.w;
    xb[u] = o;
  }
}

// ---------- pipelined 256x(64*NT) GEMM, 256 blocks, 4 phases/K-tile, 1 barrier/phase ----
// C[M,N] = A[M,K] @ B[N,K]^T.  8 waves 4M x 2N; wave tile 64 x (NT*32).
// Quadrants: ph1 (a0,b0), ph2 (a0,b1), ph3 (a1,b1), ph4 (a1,b0); 4*NT MFMA each.
// Reads are issued ONE PHASE before their consuming MFMA (drain in the LDS pipe
// under this phase's MFMA cluster); compiler auto-lgkm before the consumer.
//   ph1(t): LDB1_(t)      ph2(t): LDA_(t,a1)   ph3(t): LDB0_(t+1)   ph4(t): LDA_(t+1,a0)
// CROSS-WAVE SAFETY RULE: slot read at phase p requires every wave to have
// executed a vmcnt covering its stage, followed by a barrier, strictly before p.
// Stage plan (tile-t frame) and counted waits (FIFO-verified):
//   ph1: STG A0..A3(t+1)              (4 stages)
//   ph2: STG B2(t+1) [NT3] / B1(t+1) [NT2]; vmcnt(5)  -> covers B0,B1(t+1) for ph3 read
//   ph3: STG B0(t+2);                 vmcnt(2)  -> covers A0..A3(t+1) for ph4 read
//   ph4: STG B1(t+2) [NT3 only];      vmcnt(2|1)-> covers B2(t+1)/B1(t+1) for ph1(t+1) read
// Stage->wait distance >= 2 phases everywhere.  Adjacent-phase W/R slot pairs all
// disjoint by slot index or buffer parity (incl. slot4: ph3 writes parity t, reads
// parity t+1).  bf0 fragments are E/O double-buffered (lifetime overlaps reload);
// af/bf1 sets are dead by reload.  Tail clamps restage byte-identical data.
template <typename OutT, int NT, int MODE>
__global__ __launch_bounds__(512, 2) void gemm_pipe(
    const h16* __restrict__ A, const h16* __restrict__ B, OutT* __restrict__ C,
    int N, int K,
    const float* __restrict__ cosb, const float* __restrict__ sinb,
    h16* __restrict__ vt) {
  constexpr int NSLOT = 4 + NT;
  constexpr int BUFH  = NSLOT * 4096;               // h16 per buffer
  __shared__ __attribute__((aligned(16))) h16 SM[2 * BUFH];

  const int tid  = threadIdx.x;
  const int w    = tid >> 6, lane = tid & 63;
  const int wr   = w >> 1, wc = w & 1;              // 4M x 2N waves
  const int quad = lane >> 4, l15 = lane & 15;
  const int axr  = l15 & 7;
  const int m0 = blockIdx.y * 256, n0 = blockIdx.x * (NT * 64);

  const h16* Ab = A + (size_t)m0 * K;
  const h16* Bb = B + (size_t)n0 * K;
  const int srow = tid >> 3;                        // stage row within slot (0..63)
  const int sg8  = ((tid & 7) ^ (srow & 7)) * 8;    // pre-swizzled global k-chunk

  f32x4 acc[2][2][2][NT];                           // [a][b][mt][nt]
#pragma unroll
  for (int a = 0; a < 2; ++a)
#pragma unroll
    for (int b = 0; b < 2; ++b)
#pragma unroll
      for (int mt = 0; mt < 2; ++mt)
#pragma unroll
        for (int nt = 0; nt < NT; ++nt) acc[a][b][mt][nt] = (f32x4){0.f, 0.f, 0.f, 0.f};

  h16x8 af[2][2][2];                // [aset][mt][ks] — dead by reload phase
  h16x8 bf1[NT][2];                 // b1 fragments — dead by reload phase
  h16x8 bf0E[NT][2], bf0O[NT][2];   // b0 fragments, tile-parity double buffer

#define STG(sl_, tile_) do {                                                        \
    const h16* g_ = ((sl_) < 4) ? (Ab + (size_t)((sl_) * 64) * K)                   \
                                : (Bb + (size_t)(((sl_) - 4) * 64) * K);            \
    char* d_ = (char*)(SM + ((tile_) & 1) * BUFH + (sl_) * 4096);                   \
    gload_lds16(g_ + (size_t)srow * K + (tile_) * 64 + sg8, d_ + tid * 16);         \
  } while (0)

#define LDA_(tile_, a_) do {                                                        \
    const h16* s_ = SM + ((tile_) & 1) * BUFH + wr * 4096;                          \
    _Pragma("unroll") for (int mt = 0; mt < 2; ++mt)                                \
    _Pragma("unroll") for (int ks = 0; ks < 2; ++ks)                                \
      af[a_][mt][ks] = *(const h16x8*)&s_[((a_) * 32 + mt * 16 + l15) * 64 +        \
                                          (((ks * 4 + quad) ^ axr) * 8)];           \
  } while (0)

#define LDB1_(tile_) do {                                                           \
    const h16* s_ = SM + ((tile_) & 1) * BUFH + 16384;                              \
    _Pragma("unroll") for (int nt = 0; nt < NT; ++nt)                               \
    _Pragma("unroll") for (int ks = 0; ks < 2; ++ks)                                \
      bf1[nt][ks] = *(const h16x8*)&s_[(NT * 32 + wc * (NT * 16) + nt * 16 + l15) * 64 + \
                                       (((ks * 4 + quad) ^ axr) * 8)];              \
  } while (0)

#define LDB0_(tile_, D_) do {                                                       \
    const h16* s_ = SM + ((tile_) & 1) * BUFH + 16384;                              \
    _Pragma("unroll") for (int nt = 0; nt < NT; ++nt)                               \
    _Pragma("unroll") for (int ks = 0; ks < 2; ++ks)                                \
      D_[nt][ks] = *(const h16x8*)&s_[(wc * (NT * 16) + nt * 16 + l15) * 64 +       \
                                      (((ks * 4 + quad) ^ axr) * 8)];               \
  } while (0)

#define MMAB1(a_) do {                                                              \
    __builtin_amdgcn_s_setprio(1);                                                  \
    _Pragma("unroll") for (int mt = 0; mt < 2; ++mt)                                \
    _Pragma("unroll") for (int nt = 0; nt < NT; ++nt)                               \
    _Pragma("unroll") for (int ks = 0; ks < 2; ++ks)                                \
      acc[a_][1][mt][nt] = __builtin_amdgcn_mfma_f32_16x16x32_f16(                  \
          af[a_][mt][ks], bf1[nt][ks], acc[a_][1][mt][nt], 0, 0, 0);                \
    __builtin_amdgcn_s_setprio(0);                                                  \
  } while (0)

#define MMAB0(a_, D_) do {                                                          \
    __builtin_amdgcn_s_setprio(1);                                                  \
    _Pragma("unroll") for (int mt = 0; mt < 2; ++mt)                                \
    _Pragma("unroll") for (int nt = 0; nt < NT; ++nt)                               \
    _Pragma("unroll") for (int ks = 0; ks < 2; ++ks)                                \
      acc[a_][0][mt][nt] = __builtin_amdgcn_mfma_f32_16x16x32_f16(                  \
          af[a_][mt][ks], D_[nt][ks], acc[a_][0][mt][nt], 0, 0, 0);                 \
    __builtin_amdgcn_s_setprio(0);                                                  \
  } while (0)

#define CFENCE asm volatile("" ::: "memory")
#define BARX do { CFENCE; __builtin_amdgcn_s_barrier(); CFENCE; } while (0)
#define VM5  asm volatile("s_waitcnt vmcnt(5)" ::: "memory")
#define VM2  asm volatile("s_waitcnt vmcnt(2)" ::: "memory")
#define VMP4 do { if constexpr (NT == 3) asm volatile("s_waitcnt vmcnt(2)" ::: "memory"); \
                  else                   asm volatile("s_waitcnt vmcnt(1)" ::: "memory"); } while (0)
#define VM0  asm volatile("s_waitcnt vmcnt(0)" ::: "memory")

  const int NTILE = K >> 6;
  const int NIT   = K >> 7;

  // ---- prologue: tile0 fully staged (deadline order) + steady-state lookahead ----
  if constexpr (NT == 3) {
    STG(4, 0); STG(5, 0); STG(0, 0); STG(1, 0); STG(2, 0); STG(3, 0); STG(6, 0);
    STG(4, 1); STG(5, 1);            // lookahead: B0,B1(1)
    VMP4;                            // vmcnt(2): drains tile0's 7, leaves B0,B1(1)
  } else {
    STG(4, 0); STG(0, 0); STG(1, 0); STG(2, 0); STG(3, 0); STG(5, 0);
    STG(4, 1);                       // lookahead: B0(1)
    VMP4;                            // vmcnt(1): drains tile0's 6, leaves B0(1)
  }
  BARX;                              // after this barrier tile0 is globally visible
  LDA_(0, 0); LDB0_(0, bf0E);        // tile0 first-quadrant fragments

  for (int i = 0; i < NIT; ++i) {
    const int t0 = 2 * i, t1 = 2 * i + 1;
    const int T2 = (t0 + 2 < NTILE) ? t0 + 2 : NTILE - 1;   // tail: benign restage
    const int T3 = (t1 + 2 < NTILE) ? t1 + 2 : NTILE - 1;
    // ================= tile t0 (bf0 cur = E) =================
    LDB1_(t0);                                   // for ph2/ph3 MFMA
    STG(0, t1); STG(1, t1); STG(2, t1); STG(3, t1);
    MMAB0(0, bf0E); BARX;                        // ph1: (a0,b0)
    LDA_(t0, 1);
    if constexpr (NT == 3) STG(6, t1); else STG(5, t1);
    VM5;
    MMAB1(0); BARX;                              // ph2: (a0,b1)
    LDB0_(t1, bf0O);
    STG(4, T2);
    VM2;
    MMAB1(1); BARX;                              // ph3: (a1,b1)
    LDA_(t1, 0);
    if constexpr (NT == 3) STG(5, T2);
    VMP4;
    MMAB0(1, bf0E); BARX;                        // ph4: (a1,b0)
    // ================= tile t1 (bf0 cur = O) =================
    LDB1_(t1);
    STG(0, T2); STG(1, T2); STG(2, T2); STG(3, T2);
    MMAB0(0, bf0O); BARX;                        // ph1
    LDA_(t1, 1);
    if constexpr (NT == 3) STG(6, T2); else STG(5, T2);
    VM5;
    MMAB1(0); BARX;                              // ph2
    LDB0_(T2, bf0E);
    STG(4, T3);
    VM2;
    MMAB1(1); BARX;                              // ph3
    LDA_(T2, 0);
    if constexpr (NT == 3) STG(5, T3);
    VMP4;
    MMAB0(1, bf0O); BARX;                        // ph4
  }
  VM0;   // drain tail prefetch DMAs before LDS dealloc at wave exit

  if constexpr (MODE == 1) {
    // ---------- pure-register epilogue: RoPE (interleaved pairs) or V-transpose ----------
#pragma unroll
    for (int a = 0; a < 2; ++a)
#pragma unroll
      for (int b = 0; b < 2; ++b)
#pragma unroll
        for (int mt = 0; mt < 2; ++mt)
#pragma unroll
          for (int nt = 0; nt < NT; ++nt) {
            const int cb   = n0 + b * (NT * 32) + wc * (NT * 16) + nt * 16;
            const int row0 = m0 + wr * 64 + a * 32 + mt * 16 + quad * 4;
            if (cb >= 5120) {
              // V chunk: register transpose into vt[kv][d][s]
              const int dcol = cb + l15 - 5120;
              h16x4 vvv;
#pragma unroll
              for (int r = 0; r < 4; ++r) vvv[r] = (h16)acc[a][b][mt][nt][r];
              *(h16x4*)(vt + (size_t)dcol * SEQ + row0) = vvv;
            } else {
              // q/k chunk: RoPE with partner = lane^1 (interleaved-pair permutation)
              const int col = cb + l15;
              const int j   = (col & 127) >> 1;
              const float sgn = (col & 1) ? 1.f : -1.f;
#pragma unroll
              for (int r = 0; r < 4; ++r) {
                float own = acc[a][b][mt][nt][r];
                float par = dpp_mv<0xB1>(own);               // quad_perm(1,0,3,2): lane^1
                float cc  = cosb[(size_t)(row0 + r) * 64 + j];
                float ss  = sinb[(size_t)(row0 + r) * 64 + j];
                C[(size_t)(row0 + r) * N + col] = (OutT)(own * cc + sgn * par * ss);
              }
            }
          }
  } else {
    // plain store
#pragma unroll
    for (int a = 0; a < 2; ++a)
#pragma unroll
      for (int b = 0; b < 2; ++b)
#pragma unroll
        for (int mt = 0; mt < 2; ++mt)
#pragma unroll
          for (int nt = 0; nt < NT; ++nt)
#pragma unroll
            for (int r = 0; r < 4; ++r) {
              int row = m0 + wr * 64 + a * 32 + mt * 16 + quad * 4 + r;
              int col = n0 + b * (NT * 32) + wc * (NT * 16) + nt * 16 + l15;
              C[(size_t)row * N + col] = (OutT)acc[a][b][mt][nt][r];
            }
  }
#undef STG
#undef LDA_
#undef LDB1_
#undef LDB0_
#undef MMAB1
#undef MMAB0
#undef CFENCE
#undef BARX
#undef VM5
#undef VM2
#undef VMP4
#undef VM0
}

// ---------- flash attention: block = (h, y), 128 q-rows, 4 waves x 32 rows, BK=64 ----------
__global__ __launch_bounds__(256, 2) void flash_attn(
    const h16* __restrict__ qkv, const h16* __restrict__ vt, h16* __restrict__ o_out) {
  __shared__ __attribute__((aligned(16))) h16 Ks[64 * 128];
  __shared__ __attribute__((aligned(16))) h16 Vts[128 * 64];
  __shared__ __attribute__((aligned(16))) h16 Ps[4][32 * 72];

  const int tid  = threadIdx.x;
  const int w    = tid >> 6, lane = tid & 63;
  const int quad = lane >> 4, l15 = lane & 15;
  const int h    = blockIdx.x;
  const int y    = blockIdx.y;
  const int qt   = (y < 8) ? (15 - y) : (y - 8);   // balanced heavy/light pairing
  const int kv   = h >> 2;
  const int rowq = qt * 128 + w * 32;
  const h16* vtg = vt + (size_t)kv * HD * SEQ;

  h16x8 qf[2][4];
#pragma unroll
  for (int mt = 0; mt < 2; ++mt) {
    const h16* qrow = qkv + (size_t)(rowq + mt * 16 + l15) * QKVD + h * 128;
#pragma unroll
    for (int ks = 0; ks < 4; ++ks)
      qf[mt][ks] = *(const h16x8*)(qrow + ks * 32 + quad * 8);
  }

  f32x4 o[2][8];
#pragma unroll
  for (int mt = 0; mt < 2; ++mt)
#pragma unroll
    for (int i = 0; i < 8; ++i) o[mt][i] = (f32x4){0.f, 0.f, 0.f, 0.f};
  float mrow[2][4], lrow[2][4];
#pragma unroll
  for (int mt = 0; mt < 2; ++mt)
#pragma unroll
    for (int r = 0; r < 4; ++r) { mrow[mt][r] = -3e30f; lrow[mt][r] = 0.f; }
  h16* Psw = Ps[w];

  const int nkt = 2 * qt + 2;
  for (int kt = 0; kt < nkt; ++kt) {
    const int k0 = kt * 64;
    __syncthreads();
#pragma unroll
    for (int i = 0; i < 4; ++i) {
      int c = i * 256 + tid;
      int key = c >> 4, d8s = c & 15;
      gload_lds16(qkv + (size_t)(k0 + key) * QKVD + 4096 + kv * 128 + (d8s ^ (key & 15)) * 8,
                  (char*)Ks + c * 16);
    }
#pragma unroll
    for (int i = 0; i < 4; ++i) {
      int c = i * 256 + tid;
      int d = c >> 3, p = c & 7;
      gload_lds16(vtg + (size_t)d * SEQ + k0 + (p ^ (d & 7)) * 8,
                  (char*)Vts + c * 16);
    }
    __syncthreads();

    if (k0 <= rowq + 31) {
      const float sscale = 0.08838834764831845f;
      float alpha[2][4];
      f32x4 s2[2][4];
#pragma unroll
      for (int nt = 0; nt < 4; ++nt) {
        int key = nt * 16 + l15;
        f32x4 a0 = (f32x4){0.f, 0.f, 0.f, 0.f};
        f32x4 a1 = (f32x4){0.f, 0.f, 0.f, 0.f};
#pragma unroll
        for (int ks = 0; ks < 4; ++ks) {
          int d8 = ks * 4 + quad;
          h16x8 kf = *(const h16x8*)&Ks[key * 128 + ((d8 ^ (key & 15)) * 8)];
          a0 = __builtin_amdgcn_mfma_f32_16x16x32_f16(qf[0][ks], kf, a0, 0, 0, 0);
          a1 = __builtin_amdgcn_mfma_f32_16x16x32_f16(qf[1][ks], kf, a1, 0, 0, 0);
        }
        s2[0][nt] = a0;
        s2[1][nt] = a1;
      }
#pragma unroll
      for (int mt = 0; mt < 2; ++mt) {
#pragma unroll
        for (int r = 0; r < 4; ++r) {
          int rowg = rowq + mt * 16 + quad * 4 + r;
          float pv[4];
          float tm = -3e30f;
#pragma unroll
          for (int nt = 0; nt < 4; ++nt) {
            float v = s2[mt][nt][r] * sscale;
            if (k0 + nt * 16 + l15 > rowg) v = -3e30f;
            pv[nt] = v;
            tm = fmaxf(tm, v);
          }
          tm = red16_max(tm);
          float mnew = fmaxf(mrow[mt][r], tm);
          float a = __expf(mrow[mt][r] - mnew);
          mrow[mt][r] = mnew;
          alpha[mt][r] = a;
          float ps = 0.f;
#pragma unroll
          for (int nt = 0; nt < 4; ++nt) {
            float e = __expf(pv[nt] - mnew);
            ps += e;
            Psw[(mt * 16 + quad * 4 + r) * 72 + nt * 16 + l15] = (h16)e;
          }
          ps = red16_sum(ps);
          lrow[mt][r] = lrow[mt][r] * a + ps;
        }
      }
#pragma unroll
      for (int mt = 0; mt < 2; ++mt)
#pragma unroll
        for (int on = 0; on < 8; ++on) {
          o[mt][on][0] *= alpha[mt][0]; o[mt][on][1] *= alpha[mt][1];
          o[mt][on][2] *= alpha[mt][2]; o[mt][on][3] *= alpha[mt][3];
        }
      asm volatile("s_waitcnt lgkmcnt(0)" ::: "memory");
#pragma unroll
      for (int ks = 0; ks < 2; ++ks) {
        h16x8 pf0 = *(const h16x8*)&Psw[(0  + l15) * 72 + ks * 32 + quad * 8];
        h16x8 pf1 = *(const h16x8*)&Psw[(16 + l15) * 72 + ks * 32 + quad * 8];
        int k8 = ks * 4 + quad;
#pragma unroll
        for (int on = 0; on < 8; ++on) {
          int d = on * 16 + l15;
          h16x8 vf = *(const h16x8*)&Vts[d * 64 + ((k8 ^ (d & 7)) * 8)];
          o[0][on] = __builtin_amdgcn_mfma_f32_16x16x32_f16(pf0, vf, o[0][on], 0, 0, 0);
          o[1][on] = __builtin_amdgcn_mfma_f32_16x16x32_f16(pf1, vf, o[1][on], 0, 0, 0);
        }
      }
    }
  }
#pragma unroll
  for (int mt = 0; mt < 2; ++mt) {
    float linv[4];
#pragma unroll
    for (int r = 0; r < 4; ++r) linv[r] = 1.0f / lrow[mt][r];
#pragma unroll
    for (int on = 0; on < 8; ++on)
#pragma unroll
      for (int r = 0; r < 4; ++r) {
        int row = rowq + mt * 16 + quad * 4 + r;
        int col = h * 128 + on * 16 + l15;
        o_out[(size_t)row * DIMX + col] = (h16)(o[mt][on][r] * linv[r]);
      }
  }
}

extern "C" void kernel_launch(void* const* d_in, const int* in_sizes, int n_in,
                              void* d_out, int out_size, void* d_ws, size_t ws_size,
                              hipStream_t stream) {
  const float* x    = (const float*)d_in[0];
  const void*  wq   = d_in[1];
  const float* sq   = (const float*)d_in[2];
  const void*  wk   = d_in[3];
  const float* sk   = (const float*)d_in[4];
  const void*  wv   = d_in[5];
  const float* sv   = (const float*)d_in[6];
  const void*  wo   = d_in[7];
  const float* so   = (const float*)d_in[8];
  const float* cosb = (const float*)d_in[9];
  const float* sinb = (const float*)d_in[10];
  float* out = (float*)d_out;

  char* ws = (char*)d_ws;
  h16* Wqkv = (h16*)ws;                      // 6144*4096 h16 = 50331648 B
  h16* Wo   = (h16*)(ws + 50331648);         // 4096*4096 h16 = 33554432 B
  h16* xb   = (h16*)(ws + 83886080);         // x as h16; later attn_out
  h16* qkv  = (h16*)(ws + 100663296);        // 2048*6144 h16
  h16* vt   = (h16*)d_out;                   // vt scratch lives in d_out (dead until O-proj)

  // fused dequant (wq,wk: RoPE-pair-interleaved rows; wv,wo plain) + cast(x)
  prep_all<<<28672, 256, 0, stream>>>(wq, sq, wk, sk, wv, sv, wo, so,
                                      (const float4*)x, Wqkv, Wo, (h16x4*)xb);

  // qkv = x @ Wqkv^T, 256x192 pipelined schedule (256 blocks = 1/CU),
  // fused register RoPE (q,k) + direct V-transpose
  gemm_pipe<h16, 3, 1><<<dim3(32, 8), 512, 0, stream>>>(
      xb, Wqkv, qkv, QKVD, DIMX, cosb, sinb, vt);

  // flash attention -> attn_out (reuse xb region)
  flash_attn<<<dim3(32, 16), 256, 0, stream>>>(qkv, vt, xb);

  // out = attn_out @ Wo^T, 256x128 pipelined schedule (256 blocks = 1/CU)
  gemm_pipe<float, 2, 0><<<dim3(32, 8), 512, 0, stream>>>(
      xb, Wo, out, DIMX, DIMX, cosb, sinb, vt);
}

// Round 5
// 426.088 us; speedup vs baseline: 1.1507x; 1.0171x over previous
//
#include <hip/hip_runtime.h>
#include <stdint.h>

// Problem constants (fixed shapes)
#define DIMX 4096
#define NH   32
#define NKV  8
#define HD   128
#define SEQ  2048
#define QKVD 6144   // 4096 q + 1024 k + 1024 v

typedef _Float16 h16;
typedef __attribute__((ext_vector_type(8))) _Float16 h16x8;
typedef __attribute__((ext_vector_type(4))) _Float16 h16x4;
typedef __attribute__((ext_vector_type(4))) float   f32x4;

__device__ __forceinline__ void gload_lds16(const void* g, void* l) {
  __builtin_amdgcn_global_load_lds(
      (const __attribute__((address_space(1))) void*)g,
      (__attribute__((address_space(3))) void*)l, 16, 0, 0);
}

// ---- 16-lane reductions on the VALU via DPP reversal butterflies (no LDS pipe) ----
template <int CTRL>
__device__ __forceinline__ float dpp_mv(float x) {
  int y = __builtin_amdgcn_mov_dpp(__builtin_bit_cast(int, x), CTRL, 0xF, 0xF, true);
  return __builtin_bit_cast(float, y);
}
__device__ __forceinline__ float red16_max(float x) {
  x = fmaxf(x, dpp_mv<0xB1>(x));   // rev2
  x = fmaxf(x, dpp_mv<0x1B>(x));   // rev4
  x = fmaxf(x, dpp_mv<0x141>(x));  // rev8
  x = fmaxf(x, dpp_mv<0x140>(x));  // rev16
  return x;
}
__device__ __forceinline__ float red16_sum(float x) {
  x += dpp_mv<0xB1>(x);
  x += dpp_mv<0x1B>(x);
  x += dpp_mv<0x141>(x);
  x += dpp_mv<0x140>(x);
  return x;
}

// ---------- fused dequant (all 4 weights) + x cast ----------
// PERM=1 (q/k weights): permute out-feature rows so RoPE pairs (d, d+64) become
// adjacent interleaved columns (d' = 2*(d&63) | (d>>6)).  QK^T dot products are
// invariant under a shared per-head permutation of d, so flash_attn is unchanged;
// only the RoPE epilogue (pairing now lane^1) and cos/sin indexing (j=(col&127)>>1)
// need to know.
template <int PERM>
__device__ __forceinline__ void dq_unit(const void* __restrict__ w, const float* __restrict__ sc,
                                        h16* __restrict__ out, int u, int flag) {
  uint32_t b4;
  if (flag) {
    const int4 t = *(const int4*)((const int*)w + 4 * u);
    b4 = (uint32_t)(t.x & 0xFF) | ((uint32_t)(t.y & 0xFF) << 8) |
         ((uint32_t)(t.z & 0xFF) << 16) | ((uint32_t)(t.w & 0xFF) << 24);
  } else {
    b4 = ((const uint32_t*)w)[u];
  }
  int r = u >> 4;
  int p = (u & 15) * 4;
  float shi = sc[2 * r], slo = sc[2 * r + 1];
  h16x4 hi, lo;
#pragma unroll
  for (int j = 0; j < 4; ++j) {
    int by = (int)((b4 >> (8 * j)) & 0xFF);
    int hn = (by << 24) >> 28;
    int ln = (by << 28) >> 28;
    hi[j] = (h16)((float)hn * shi);
    lo[j] = (h16)((float)ln * slo);
  }
  size_t base;
  if (PERM) {
    int row  = r >> 5;                                           // out-feature row
    int rowp = (row & ~127) | (((row & 63) << 1) | ((row >> 6) & 1));
    base = ((size_t)rowp << 12) + (size_t)((r & 31) << 7);
  } else {
    base = (size_t)r << 7;
  }
  *(h16x4*)(out + base + p)      = hi;
  *(h16x4*)(out + base + 64 + p) = lo;
}

#define U_WQ 2097152
#define U_WK 524288
#define U_WV 524288
#define U_WO 2097152

__global__ __launch_bounds__(256) void prep_all(
    const void* __restrict__ wq, const float* __restrict__ sq,
    const void* __restrict__ wk, const float* __restrict__ sk,
    const void* __restrict__ wv, const float* __restrict__ sv,
    const void* __restrict__ wo, const float* __restrict__ so,
    const float4* __restrict__ x,
    h16* __restrict__ Wqkv, h16* __restrict__ Wo, h16x4* __restrict__ xb) {
  __shared__ int sfl;
  if (threadIdx.x == 0) {
    int ok = 1;
    const int* wi = (const int*)wq;
    for (int i = 0; i < 64; ++i) {
      int v = wi[i];
      if (v < -128 || v > 127) ok = 0;
    }
    sfl = ok;
  }
  __syncthreads();
  const int fl = sfl;
  int u = blockIdx.x * 256 + threadIdx.x;
  if (u < U_WQ) { dq_unit<1>(wq, sq, Wqkv, u, fl); return; }
  u -= U_WQ;
  if (u < U_WK) { dq_unit<1>(wk, sk, Wqkv + 16777216, u, fl); return; }
  u -= U_WK;
  if (u < U_WV) { dq_unit<0>(wv, sv, Wqkv + 20971520, u, fl); return; }
  u -= U_WV;
  if (u < U_WO) { dq_unit<0>(wo, so, Wo, u, fl); return; }
  u -= U_WO;
  {
    float4 v = x[u];
    h16x4 o;
    o.x = (h16)v.x; o.y = (h16)v.y; o.z = (h16)v.z; o.w = (h16)v.w;
    xb[u] = o;
  }
}

// ---------- pipelined 256x(64*NT) GEMM, 256 blocks, 4 phases/K-tile, 1 barrier/phase ----
// C[M,N] = A[M,K] @ B[N,K]^T.  8 waves 4M x 2N; wave tile 64 x (NT*32).
// Quadrants: ph1 (a0,b0), ph2 (a0,b1), ph3 (a1,b1), ph4 (a1,b0); 4*NT MFMA each.
// ds_reads issued ONE PHASE before their consuming MFMA (drain under this phase's
// MFMA); global staging issued TWO TILES ahead (t+2, ACTIVE-parity buffer):
// each slot's tile-t reads are lgkm-drained before the consuming wave's barrier
// arrival (drain precedes MFMA precedes barrier), so slot s is write-free from:
//   slot4: ph2(t)   [LDB0_(t) issued ph3(t-1), consumed ph1(t)]
//   slot5,6: ph3(t) [LDB1_(t) issued ph1(t),   consumed ph2(t)]
//   slot0-3: ph4(t) [LDA_(t,1) issued ph2(t),  consumed ph3(t)]
// Stage plan (frame t, tile t+2):  ph2: slot4; ph3: slot5[,6]; ph4: slot0-3.
// Counted waits (FIFO-verified, steady state; loads/frame = 4+NT):
//   ph2 (after STG4):   NT3 vmcnt(7) / NT2 vmcnt(6)  -> drains slot4(t+1), 4 phases old
//   ph3 (after STG5/6): NT3 vmcnt(3) / NT2 vmcnt(2)  -> drains A(t+1) (3 ph) + B1/2(t+1) (4 ph)
//   ph1, ph4: no wait.  Minimum stage->wait slack >= 3 phases (>> DMA latency).
// Cross-wave: every covered read is preceded (in EVERY wave) by a covering vmcnt
// + a barrier.  Same-phase W/R pairs disjoint by slot or parity.  Tail clamps
// rewrite byte-identical data to the same physical slot (benign).
template <typename OutT, int NT, int MODE>
__global__ __launch_bounds__(512, 2) void gemm_pipe(
    const h16* __restrict__ A, const h16* __restrict__ B, OutT* __restrict__ C,
    int N, int K,
    const float* __restrict__ cosb, const float* __restrict__ sinb,
    h16* __restrict__ vt) {
  constexpr int NSLOT = 4 + NT;
  constexpr int BUFH  = NSLOT * 4096;               // h16 per buffer
  __shared__ __attribute__((aligned(16))) h16 SM[2 * BUFH];

  const int tid  = threadIdx.x;
  const int w    = tid >> 6, lane = tid & 63;
  const int wr   = w >> 1, wc = w & 1;              // 4M x 2N waves
  const int quad = lane >> 4, l15 = lane & 15;
  const int axr  = l15 & 7;
  const int m0 = blockIdx.y * 256, n0 = blockIdx.x * (NT * 64);

  const h16* Ab = A + (size_t)m0 * K;
  const h16* Bb = B + (size_t)n0 * K;
  const int srow = tid >> 3;                        // stage row within slot (0..63)
  const int sg8  = ((tid & 7) ^ (srow & 7)) * 8;    // pre-swizzled global k-chunk

  f32x4 acc[2][2][2][NT];                           // [a][b][mt][nt]
#pragma unroll
  for (int a = 0; a < 2; ++a)
#pragma unroll
    for (int b = 0; b < 2; ++b)
#pragma unroll
      for (int mt = 0; mt < 2; ++mt)
#pragma unroll
        for (int nt = 0; nt < NT; ++nt) acc[a][b][mt][nt] = (f32x4){0.f, 0.f, 0.f, 0.f};

  h16x8 af[2][2][2];                // [aset][mt][ks] — dead by reload phase
  h16x8 bf1[NT][2];                 // b1 fragments — dead by reload phase
  h16x8 bf0E[NT][2], bf0O[NT][2];   // b0 fragments, tile-parity double buffer

#define STG(sl_, tile_) do {                                                        \
    const h16* g_ = ((sl_) < 4) ? (Ab + (size_t)((sl_) * 64) * K)                   \
                                : (Bb + (size_t)(((sl_) - 4) * 64) * K);            \
    char* d_ = (char*)(SM + ((tile_) & 1) * BUFH + (sl_) * 4096);                   \
    gload_lds16(g_ + (size_t)srow * K + (tile_) * 64 + sg8, d_ + tid * 16);         \
  } while (0)

#define LDA_(tile_, a_) do {                                                        \
    const h16* s_ = SM + ((tile_) & 1) * BUFH + wr * 4096;                          \
    _Pragma("unroll") for (int mt = 0; mt < 2; ++mt)                                \
    _Pragma("unroll") for (int ks = 0; ks < 2; ++ks)                                \
      af[a_][mt][ks] = *(const h16x8*)&s_[((a_) * 32 + mt * 16 + l15) * 64 +        \
                                          (((ks * 4 + quad) ^ axr) * 8)];           \
  } while (0)

#define LDB1_(tile_) do {                                                           \
    const h16* s_ = SM + ((tile_) & 1) * BUFH + 16384;                              \
    _Pragma("unroll") for (int nt = 0; nt < NT; ++nt)                               \
    _Pragma("unroll") for (int ks = 0; ks < 2; ++ks)                                \
      bf1[nt][ks] = *(const h16x8*)&s_[(NT * 32 + wc * (NT * 16) + nt * 16 + l15) * 64 + \
                                       (((ks * 4 + quad) ^ axr) * 8)];              \
  } while (0)

#define LDB0_(tile_, D_) do {                                                       \
    const h16* s_ = SM + ((tile_) & 1) * BUFH + 16384;                              \
    _Pragma("unroll") for (int nt = 0; nt < NT; ++nt)                               \
    _Pragma("unroll") for (int ks = 0; ks < 2; ++ks)                                \
      D_[nt][ks] = *(const h16x8*)&s_[(wc * (NT * 16) + nt * 16 + l15) * 64 +       \
                                      (((ks * 4 + quad) ^ axr) * 8)];               \
  } while (0)

#define MMAB1(a_) do {                                                              \
    __builtin_amdgcn_s_setprio(1);                                                  \
    _Pragma("unroll") for (int mt = 0; mt < 2; ++mt)                                \
    _Pragma("unroll") for (int nt = 0; nt < NT; ++nt)                               \
    _Pragma("unroll") for (int ks = 0; ks < 2; ++ks)                                \
      acc[a_][1][mt][nt] = __builtin_amdgcn_mfma_f32_16x16x32_f16(                  \
          af[a_][mt][ks], bf1[nt][ks], acc[a_][1][mt][nt], 0, 0, 0);                \
    __builtin_amdgcn_s_setprio(0);                                                  \
  } while (0)

#define MMAB0(a_, D_) do {                                                          \
    __builtin_amdgcn_s_setprio(1);                                                  \
    _Pragma("unroll") for (int mt = 0; mt < 2; ++mt)                                \
    _Pragma("unroll") for (int nt = 0; nt < NT; ++nt)                               \
    _Pragma("unroll") for (int ks = 0; ks < 2; ++ks)                                \
      acc[a_][0][mt][nt] = __builtin_amdgcn_mfma_f32_16x16x32_f16(                  \
          af[a_][mt][ks], D_[nt][ks], acc[a_][0][mt][nt], 0, 0, 0);                 \
    __builtin_amdgcn_s_setprio(0);                                                  \
  } while (0)

#define CFENCE asm volatile("" ::: "memory")
#define BARX do { CFENCE; __builtin_amdgcn_s_barrier(); CFENCE; } while (0)
#define W2 do { if constexpr (NT == 3) asm volatile("s_waitcnt vmcnt(7)" ::: "memory"); \
                else                   asm volatile("s_waitcnt vmcnt(6)" ::: "memory"); } while (0)
#define W3 do { if constexpr (NT == 3) asm volatile("s_waitcnt vmcnt(3)" ::: "memory"); \
                else                   asm volatile("s_waitcnt vmcnt(2)" ::: "memory"); } while (0)
#define VM0  asm volatile("s_waitcnt vmcnt(0)" ::: "memory")

  const int NTILE = K >> 6;
  const int NIT   = K >> 7;

  // ---- prologue: stage tiles 0 and 1 in steady-state FIFO order {B0, B1[,B2], A0-3} ----
  STG(4, 0); STG(5, 0);
  if constexpr (NT == 3) STG(6, 0);
  STG(0, 0); STG(1, 0); STG(2, 0); STG(3, 0);
  STG(4, 1); STG(5, 1);
  if constexpr (NT == 3) STG(6, 1);
  STG(0, 1); STG(1, 1); STG(2, 1); STG(3, 1);
  W2;                                // drains all of tile0; leaves tile1 (4+NT) in flight
  BARX;                              // tile0 globally visible
  LDA_(0, 0); LDB0_(0, bf0E);        // tile0 first-quadrant fragments (pre-issued)

  for (int i = 0; i < NIT; ++i) {
    const int t0 = 2 * i, t1 = 2 * i + 1;
    const int T2 = (t0 + 2 < NTILE) ? t0 + 2 : NTILE - 1;   // tail: benign identical restage
    const int T3 = (t1 + 2 < NTILE) ? t1 + 2 : NTILE - 1;
    // ================= frame t0 (bf0 cur = E) =================
    LDB1_(t0);
    MMAB0(0, bf0E); BARX;                        // ph1: (a0,b0)
    LDA_(t0, 1); STG(4, T2); W2;
    MMAB1(0); BARX;                              // ph2: (a0,b1)
    LDB0_(t1, bf0O); STG(5, T2);
    if constexpr (NT == 3) STG(6, T2);
    W3;
    MMAB1(1); BARX;                              // ph3: (a1,b1)
    LDA_(t1, 0); STG(0, T2); STG(1, T2); STG(2, T2); STG(3, T2);
    MMAB0(1, bf0E); BARX;                        // ph4: (a1,b0)
    // ================= frame t1 (bf0 cur = O) =================
    LDB1_(t1);
    MMAB0(0, bf0O); BARX;                        // ph1
    LDA_(t1, 1); STG(4, T3); W2;
    MMAB1(0); BARX;                              // ph2
    LDB0_(T2, bf0E); STG(5, T3);
    if constexpr (NT == 3) STG(6, T3);
    W3;
    MMAB1(1); BARX;                              // ph3
    LDA_(T2, 0); STG(0, T3); STG(1, T3); STG(2, T3); STG(3, T3);
    MMAB0(1, bf0O); BARX;                        // ph4
  }
  VM0;   // drain tail prefetch DMAs before LDS dealloc at wave exit

  if constexpr (MODE == 1) {
    // ---------- pure-register epilogue: RoPE (interleaved pairs) or V-transpose ----------
#pragma unroll
    for (int a = 0; a < 2; ++a)
#pragma unroll
      for (int b = 0; b < 2; ++b)
#pragma unroll
        for (int mt = 0; mt < 2; ++mt)
#pragma unroll
          for (int nt = 0; nt < NT; ++nt) {
            const int cb   = n0 + b * (NT * 32) + wc * (NT * 16) + nt * 16;
            const int row0 = m0 + wr * 64 + a * 32 + mt * 16 + quad * 4;
            if (cb >= 5120) {
              // V chunk: register transpose into vt[kv][d][s]
              const int dcol = cb + l15 - 5120;
              h16x4 vvv;
#pragma unroll
              for (int r = 0; r < 4; ++r) vvv[r] = (h16)acc[a][b][mt][nt][r];
              *(h16x4*)(vt + (size_t)dcol * SEQ + row0) = vvv;
            } else {
              // q/k chunk: RoPE with partner = lane^1 (interleaved-pair permutation)
              const int col = cb + l15;
              const int j   = (col & 127) >> 1;
              const float sgn = (col & 1) ? 1.f : -1.f;
#pragma unroll
              for (int r = 0; r < 4; ++r) {
                float own = acc[a][b][mt][nt][r];
                float par = dpp_mv<0xB1>(own);               // quad_perm(1,0,3,2): lane^1
                float cc  = cosb[(size_t)(row0 + r) * 64 + j];
                float ss  = sinb[(size_t)(row0 + r) * 64 + j];
                C[(size_t)(row0 + r) * N + col] = (OutT)(own * cc + sgn * par * ss);
              }
            }
          }
  } else {
    // plain store
#pragma unroll
    for (int a = 0; a < 2; ++a)
#pragma unroll
      for (int b = 0; b < 2; ++b)
#pragma unroll
        for (int mt = 0; mt < 2; ++mt)
#pragma unroll
          for (int nt = 0; nt < NT; ++nt)
#pragma unroll
            for (int r = 0; r < 4; ++r) {
              int row = m0 + wr * 64 + a * 32 + mt * 16 + quad * 4 + r;
              int col = n0 + b * (NT * 32) + wc * (NT * 16) + nt * 16 + l15;
              C[(size_t)row * N + col] = (OutT)acc[a][b][mt][nt][r];
            }
  }
#undef STG
#undef LDA_
#undef LDB1_
#undef LDB0_
#undef MMAB1
#undef MMAB0
#undef CFENCE
#undef BARX
#undef W2
#undef W3
#undef VM0
}

// ---------- flash attention: block = (h, y), 128 q-rows, 4 waves x 32 rows, BK=64 ----------
__global__ __launch_bounds__(256, 2) void flash_attn(
    const h16* __restrict__ qkv, const h16* __restrict__ vt, h16* __restrict__ o_out) {
  __shared__ __attribute__((aligned(16))) h16 Ks[64 * 128];
  __shared__ __attribute__((aligned(16))) h16 Vts[128 * 64];
  __shared__ __attribute__((aligned(16))) h16 Ps[4][32 * 72];

  const int tid  = threadIdx.x;
  const int w    = tid >> 6, lane = tid & 63;
  const int quad = lane >> 4, l15 = lane & 15;
  const int h    = blockIdx.x;
  const int y    = blockIdx.y;
  const int qt   = (y < 8) ? (15 - y) : (y - 8);   // balanced heavy/light pairing
  const int kv   = h >> 2;
  const int rowq = qt * 128 + w * 32;
  const h16* vtg = vt + (size_t)kv * HD * SEQ;

  h16x8 qf[2][4];
#pragma unroll
  for (int mt = 0; mt < 2; ++mt) {
    const h16* qrow = qkv + (size_t)(rowq + mt * 16 + l15) * QKVD + h * 128;
#pragma unroll
    for (int ks = 0; ks < 4; ++ks)
      qf[mt][ks] = *(const h16x8*)(qrow + ks * 32 + quad * 8);
  }

  f32x4 o[2][8];
#pragma unroll
  for (int mt = 0; mt < 2; ++mt)
#pragma unroll
    for (int i = 0; i < 8; ++i) o[mt][i] = (f32x4){0.f, 0.f, 0.f, 0.f};
  float mrow[2][4], lrow[2][4];
#pragma unroll
  for (int mt = 0; mt < 2; ++mt)
#pragma unroll
    for (int r = 0; r < 4; ++r) { mrow[mt][r] = -3e30f; lrow[mt][r] = 0.f; }
  h16* Psw = Ps[w];

  const int nkt = 2 * qt + 2;
  for (int kt = 0; kt < nkt; ++kt) {
    const int k0 = kt * 64;
    __syncthreads();
#pragma unroll
    for (int i = 0; i < 4; ++i) {
      int c = i * 256 + tid;
      int key = c >> 4, d8s = c & 15;
      gload_lds16(qkv + (size_t)(k0 + key) * QKVD + 4096 + kv * 128 + (d8s ^ (key & 15)) * 8,
                  (char*)Ks + c * 16);
    }
#pragma unroll
    for (int i = 0; i < 4; ++i) {
      int c = i * 256 + tid;
      int d = c >> 3, p = c & 7;
      gload_lds16(vtg + (size_t)d * SEQ + k0 + (p ^ (d & 7)) * 8,
                  (char*)Vts + c * 16);
    }
    __syncthreads();

    if (k0 <= rowq + 31) {
      const float sscale = 0.08838834764831845f;
      float alpha[2][4];
      f32x4 s2[2][4];
#pragma unroll
      for (int nt = 0; nt < 4; ++nt) {
        int key = nt * 16 + l15;
        f32x4 a0 = (f32x4){0.f, 0.f, 0.f, 0.f};
        f32x4 a1 = (f32x4){0.f, 0.f, 0.f, 0.f};
#pragma unroll
        for (int ks = 0; ks < 4; ++ks) {
          int d8 = ks * 4 + quad;
          h16x8 kf = *(const h16x8*)&Ks[key * 128 + ((d8 ^ (key & 15)) * 8)];
          a0 = __builtin_amdgcn_mfma_f32_16x16x32_f16(qf[0][ks], kf, a0, 0, 0, 0);
          a1 = __builtin_amdgcn_mfma_f32_16x16x32_f16(qf[1][ks], kf, a1, 0, 0, 0);
        }
        s2[0][nt] = a0;
        s2[1][nt] = a1;
      }
#pragma unroll
      for (int mt = 0; mt < 2; ++mt) {
#pragma unroll
        for (int r = 0; r < 4; ++r) {
          int rowg = rowq + mt * 16 + quad * 4 + r;
          float pv[4];
          float tm = -3e30f;
#pragma unroll
          for (int nt = 0; nt < 4; ++nt) {
            float v = s2[mt][nt][r] * sscale;
            if (k0 + nt * 16 + l15 > rowg) v = -3e30f;
            pv[nt] = v;
            tm = fmaxf(tm, v);
          }
          tm = red16_max(tm);
          float mnew = fmaxf(mrow[mt][r], tm);
          float a = __expf(mrow[mt][r] - mnew);
          mrow[mt][r] = mnew;
          alpha[mt][r] = a;
          float ps = 0.f;
#pragma unroll
          for (int nt = 0; nt < 4; ++nt) {
            float e = __expf(pv[nt] - mnew);
            ps += e;
            Psw[(mt * 16 + quad * 4 + r) * 72 + nt * 16 + l15] = (h16)e;
          }
          ps = red16_sum(ps);
          lrow[mt][r] = lrow[mt][r] * a + ps;
        }
      }
#pragma unroll
      for (int mt = 0; mt < 2; ++mt)
#pragma unroll
        for (int on = 0; on < 8; ++on) {
          o[mt][on][0] *= alpha[mt][0]; o[mt][on][1] *= alpha[mt][1];
          o[mt][on][2] *= alpha[mt][2]; o[mt][on][3] *= alpha[mt][3];
        }
      asm volatile("s_waitcnt lgkmcnt(0)" ::: "memory");
#pragma unroll
      for (int ks = 0; ks < 2; ++ks) {
        h16x8 pf0 = *(const h16x8*)&Psw[(0  + l15) * 72 + ks * 32 + quad * 8];
        h16x8 pf1 = *(const h16x8*)&Psw[(16 + l15) * 72 + ks * 32 + quad * 8];
        int k8 = ks * 4 + quad;
#pragma unroll
        for (int on = 0; on < 8; ++on) {
          int d = on * 16 + l15;
          h16x8 vf = *(const h16x8*)&Vts[d * 64 + ((k8 ^ (d & 7)) * 8)];
          o[0][on] = __builtin_amdgcn_mfma_f32_16x16x32_f16(pf0, vf, o[0][on], 0, 0, 0);
          o[1][on] = __builtin_amdgcn_mfma_f32_16x16x32_f16(pf1, vf, o[1][on], 0, 0, 0);
        }
      }
    }
  }
#pragma unroll
  for (int mt = 0; mt < 2; ++mt) {
    float linv[4];
#pragma unroll
    for (int r = 0; r < 4; ++r) linv[r] = 1.0f / lrow[mt][r];
#pragma unroll
    for (int on = 0; on < 8; ++on)
#pragma unroll
      for (int r = 0; r < 4; ++r) {
        int row = rowq + mt * 16 + quad * 4 + r;
        int col = h * 128 + on * 16 + l15;
        o_out[(size_t)row * DIMX + col] = (h16)(o[mt][on][r] * linv[r]);
      }
  }
}

extern "C" void kernel_launch(void* const* d_in, const int* in_sizes, int n_in,
                              void* d_out, int out_size, void* d_ws, size_t ws_size,
                              hipStream_t stream) {
  const float* x    = (const float*)d_in[0];
  const void*  wq   = d_in[1];
  const float* sq   = (const float*)d_in[2];
  const void*  wk   = d_in[3];
  const float* sk   = (const float*)d_in[4];
  const void*  wv   = d_in[5];
  const float* sv   = (const float*)d_in[6];
  const void*  wo   = d_in[7];
  const float* so   = (const float*)d_in[8];
  const float* cosb = (const float*)d_in[9];
  const float* sinb = (const float*)d_in[10];
  float* out = (float*)d_out;

  char* ws = (char*)d_ws;
  h16* Wqkv = (h16*)ws;                      // 6144*4096 h16 = 50331648 B
  h16* Wo   = (h16*)(ws + 50331648);         // 4096*4096 h16 = 33554432 B
  h16* xb   = (h16*)(ws + 83886080);         // x as h16; later attn_out
  h16* qkv  = (h16*)(ws + 100663296);        // 2048*6144 h16
  h16* vt   = (h16*)d_out;                   // vt scratch lives in d_out (dead until O-proj)

  // fused dequant (wq,wk: RoPE-pair-interleaved rows; wv,wo plain) + cast(x)
  prep_all<<<28672, 256, 0, stream>>>(wq, sq, wk, sk, wv, sv, wo, so,
                                      (const float4*)x, Wqkv, Wo, (h16x4*)xb);

  // qkv = x @ Wqkv^T, 256x192 pipelined schedule (256 blocks = 1/CU),
  // fused register RoPE (q,k) + direct V-transpose
  gemm_pipe<h16, 3, 1><<<dim3(32, 8), 512, 0, stream>>>(
      xb, Wqkv, qkv, QKVD, DIMX, cosb, sinb, vt);

  // flash attention -> attn_out (reuse xb region)
  flash_attn<<<dim3(32, 16), 256, 0, stream>>>(qkv, vt, xb);

  // out = attn_out @ Wo^T, 256x128 pipelined schedule (256 blocks = 1/CU)
  gemm_pipe<float, 2, 0><<<dim3(32, 8), 512, 0, stream>>>(
      xb, Wo, out, DIMX, DIMX, cosb, sinb, vt);
}

// Round 6
// 415.136 us; speedup vs baseline: 1.1811x; 1.0264x over previous
//
#include <hip/hip_runtime.h>
#include <stdint.h>

// Problem constants (fixed shapes)
#define DIMX 4096
#define NH   32
#define NKV  8
#define HD   128
#define SEQ  2048
#define QKVD 6144   // 4096 q + 1024 k + 1024 v

typedef _Float16 h16;
typedef __attribute__((ext_vector_type(8))) _Float16 h16x8;
typedef __attribute__((ext_vector_type(4))) _Float16 h16x4;
typedef __attribute__((ext_vector_type(4))) float   f32x4;

__device__ __forceinline__ void gload_lds16(const void* g, void* l) {
  __builtin_amdgcn_global_load_lds(
      (const __attribute__((address_space(1))) void*)g,
      (__attribute__((address_space(3))) void*)l, 16, 0, 0);
}

// ---- 16-lane reductions on the VALU via DPP reversal butterflies (no LDS pipe) ----
template <int CTRL>
__device__ __forceinline__ float dpp_mv(float x) {
  int y = __builtin_amdgcn_mov_dpp(__builtin_bit_cast(int, x), CTRL, 0xF, 0xF, true);
  return __builtin_bit_cast(float, y);
}
__device__ __forceinline__ float red16_max(float x) {
  x = fmaxf(x, dpp_mv<0xB1>(x));   // rev2
  x = fmaxf(x, dpp_mv<0x1B>(x));   // rev4
  x = fmaxf(x, dpp_mv<0x141>(x));  // rev8
  x = fmaxf(x, dpp_mv<0x140>(x));  // rev16
  return x;
}
__device__ __forceinline__ float red16_sum(float x) {
  x += dpp_mv<0xB1>(x);
  x += dpp_mv<0x1B>(x);
  x += dpp_mv<0x141>(x);
  x += dpp_mv<0x140>(x);
  return x;
}

// ---------- fused dequant (all 4 weights) + x cast ----------
// PERM=1 (q/k weights): permute out-feature rows so RoPE pairs (d, d+64) become
// adjacent interleaved columns (d' = 2*(d&63) | (d>>6)).  QK^T dot products are
// invariant under a shared per-head permutation of d, so flash_attn is unchanged;
// only the RoPE epilogue (pairing now lane^1) and cos/sin indexing (j=(col&127)>>1)
// need to know.
template <int PERM>
__device__ __forceinline__ void dq_unit(const void* __restrict__ w, const float* __restrict__ sc,
                                        h16* __restrict__ out, int u, int flag) {
  uint32_t b4;
  if (flag) {
    const int4 t = *(const int4*)((const int*)w + 4 * u);
    b4 = (uint32_t)(t.x & 0xFF) | ((uint32_t)(t.y & 0xFF) << 8) |
         ((uint32_t)(t.z & 0xFF) << 16) | ((uint32_t)(t.w & 0xFF) << 24);
  } else {
    b4 = ((const uint32_t*)w)[u];
  }
  int r = u >> 4;
  int p = (u & 15) * 4;
  float shi = sc[2 * r], slo = sc[2 * r + 1];
  h16x4 hi, lo;
#pragma unroll
  for (int j = 0; j < 4; ++j) {
    int by = (int)((b4 >> (8 * j)) & 0xFF);
    int hn = (by << 24) >> 28;
    int ln = (by << 28) >> 28;
    hi[j] = (h16)((float)hn * shi);
    lo[j] = (h16)((float)ln * slo);
  }
  size_t base;
  if (PERM) {
    int row  = r >> 5;                                           // out-feature row
    int rowp = (row & ~127) | (((row & 63) << 1) | ((row >> 6) & 1));
    base = ((size_t)rowp << 12) + (size_t)((r & 31) << 7);
  } else {
    base = (size_t)r << 7;
  }
  *(h16x4*)(out + base + p)      = hi;
  *(h16x4*)(out + base + 64 + p) = lo;
}

#define U_WQ 2097152
#define U_WK 524288
#define U_WV 524288
#define U_WO 2097152

__global__ __launch_bounds__(256) void prep_all(
    const void* __restrict__ wq, const float* __restrict__ sq,
    const void* __restrict__ wk, const float* __restrict__ sk,
    const void* __restrict__ wv, const float* __restrict__ sv,
    const void* __restrict__ wo, const float* __restrict__ so,
    const float4* __restrict__ x,
    h16* __restrict__ Wqkv, h16* __restrict__ Wo, h16x4* __restrict__ xb) {
  __shared__ int sfl;
  if (threadIdx.x == 0) {
    int ok = 1;
    const int* wi = (const int*)wq;
    for (int i = 0; i < 64; ++i) {
      int v = wi[i];
      if (v < -128 || v > 127) ok = 0;
    }
    sfl = ok;
  }
  __syncthreads();
  const int fl = sfl;
  int u = blockIdx.x * 256 + threadIdx.x;
  if (u < U_WQ) { dq_unit<1>(wq, sq, Wqkv, u, fl); return; }
  u -= U_WQ;
  if (u < U_WK) { dq_unit<1>(wk, sk, Wqkv + 16777216, u, fl); return; }
  u -= U_WK;
  if (u < U_WV) { dq_unit<0>(wv, sv, Wqkv + 20971520, u, fl); return; }
  u -= U_WV;
  if (u < U_WO) { dq_unit<0>(wo, so, Wo, u, fl); return; }
  u -= U_WO;
  {
    float4 v = x[u];
    h16x4 o;
    o.x = (h16)v.x; o.y = (h16)v.y; o.z = (h16)v.z; o.w = (h16)v.w;
    xb[u] = o;
  }
}

// ---------- pipelined 256x(64*NT) GEMM, 256 blocks, 4 phases/K-tile, 1 barrier/phase ----
// (structure measured-good in r5: both GEMMs below 105 us; unchanged this round
// except the q-only 1/sqrt(128) fold in the RoPE epilogue.)
template <typename OutT, int NT, int MODE>
__global__ __launch_bounds__(512, 2) void gemm_pipe(
    const h16* __restrict__ A, const h16* __restrict__ B, OutT* __restrict__ C,
    int N, int K,
    const float* __restrict__ cosb, const float* __restrict__ sinb,
    h16* __restrict__ vt) {
  constexpr int NSLOT = 4 + NT;
  constexpr int BUFH  = NSLOT * 4096;               // h16 per buffer
  __shared__ __attribute__((aligned(16))) h16 SM[2 * BUFH];

  const int tid  = threadIdx.x;
  const int w    = tid >> 6, lane = tid & 63;
  const int wr   = w >> 1, wc = w & 1;              // 4M x 2N waves
  const int quad = lane >> 4, l15 = lane & 15;
  const int axr  = l15 & 7;
  const int m0 = blockIdx.y * 256, n0 = blockIdx.x * (NT * 64);

  const h16* Ab = A + (size_t)m0 * K;
  const h16* Bb = B + (size_t)n0 * K;
  const int srow = tid >> 3;                        // stage row within slot (0..63)
  const int sg8  = ((tid & 7) ^ (srow & 7)) * 8;    // pre-swizzled global k-chunk

  f32x4 acc[2][2][2][NT];                           // [a][b][mt][nt]
#pragma unroll
  for (int a = 0; a < 2; ++a)
#pragma unroll
    for (int b = 0; b < 2; ++b)
#pragma unroll
      for (int mt = 0; mt < 2; ++mt)
#pragma unroll
        for (int nt = 0; nt < NT; ++nt) acc[a][b][mt][nt] = (f32x4){0.f, 0.f, 0.f, 0.f};

  h16x8 af[2][2][2];                // [aset][mt][ks] — dead by reload phase
  h16x8 bf1[NT][2];                 // b1 fragments — dead by reload phase
  h16x8 bf0E[NT][2], bf0O[NT][2];   // b0 fragments, tile-parity double buffer

#define STG(sl_, tile_) do {                                                        \
    const h16* g_ = ((sl_) < 4) ? (Ab + (size_t)((sl_) * 64) * K)                   \
                                : (Bb + (size_t)(((sl_) - 4) * 64) * K);            \
    char* d_ = (char*)(SM + ((tile_) & 1) * BUFH + (sl_) * 4096);                   \
    gload_lds16(g_ + (size_t)srow * K + (tile_) * 64 + sg8, d_ + tid * 16);         \
  } while (0)

#define LDA_(tile_, a_) do {                                                        \
    const h16* s_ = SM + ((tile_) & 1) * BUFH + wr * 4096;                          \
    _Pragma("unroll") for (int mt = 0; mt < 2; ++mt)                                \
    _Pragma("unroll") for (int ks = 0; ks < 2; ++ks)                                \
      af[a_][mt][ks] = *(const h16x8*)&s_[((a_) * 32 + mt * 16 + l15) * 64 +        \
                                          (((ks * 4 + quad) ^ axr) * 8)];           \
  } while (0)

#define LDB1_(tile_) do {                                                           \
    const h16* s_ = SM + ((tile_) & 1) * BUFH + 16384;                              \
    _Pragma("unroll") for (int nt = 0; nt < NT; ++nt)                               \
    _Pragma("unroll") for (int ks = 0; ks < 2; ++ks)                                \
      bf1[nt][ks] = *(const h16x8*)&s_[(NT * 32 + wc * (NT * 16) + nt * 16 + l15) * 64 + \
                                       (((ks * 4 + quad) ^ axr) * 8)];              \
  } while (0)

#define LDB0_(tile_, D_) do {                                                       \
    const h16* s_ = SM + ((tile_) & 1) * BUFH + 16384;                              \
    _Pragma("unroll") for (int nt = 0; nt < NT; ++nt)                               \
    _Pragma("unroll") for (int ks = 0; ks < 2; ++ks)                                \
      D_[nt][ks] = *(const h16x8*)&s_[(wc * (NT * 16) + nt * 16 + l15) * 64 +       \
                                      (((ks * 4 + quad) ^ axr) * 8)];               \
  } while (0)

#define MMAB1(a_) do {                                                              \
    __builtin_amdgcn_s_setprio(1);                                                  \
    _Pragma("unroll") for (int mt = 0; mt < 2; ++mt)                                \
    _Pragma("unroll") for (int nt = 0; nt < NT; ++nt)                               \
    _Pragma("unroll") for (int ks = 0; ks < 2; ++ks)                                \
      acc[a_][1][mt][nt] = __builtin_amdgcn_mfma_f32_16x16x32_f16(                  \
          af[a_][mt][ks], bf1[nt][ks], acc[a_][1][mt][nt], 0, 0, 0);                \
    __builtin_amdgcn_s_setprio(0);                                                  \
  } while (0)

#define MMAB0(a_, D_) do {                                                          \
    __builtin_amdgcn_s_setprio(1);                                                  \
    _Pragma("unroll") for (int mt = 0; mt < 2; ++mt)                                \
    _Pragma("unroll") for (int nt = 0; nt < NT; ++nt)                               \
    _Pragma("unroll") for (int ks = 0; ks < 2; ++ks)                                \
      acc[a_][0][mt][nt] = __builtin_amdgcn_mfma_f32_16x16x32_f16(                  \
          af[a_][mt][ks], D_[nt][ks], acc[a_][0][mt][nt], 0, 0, 0);                 \
    __builtin_amdgcn_s_setprio(0);                                                  \
  } while (0)

#define CFENCE asm volatile("" ::: "memory")
#define BARX do { CFENCE; __builtin_amdgcn_s_barrier(); CFENCE; } while (0)
#define W2 do { if constexpr (NT == 3) asm volatile("s_waitcnt vmcnt(7)" ::: "memory"); \
                else                   asm volatile("s_waitcnt vmcnt(6)" ::: "memory"); } while (0)
#define W3 do { if constexpr (NT == 3) asm volatile("s_waitcnt vmcnt(3)" ::: "memory"); \
                else                   asm volatile("s_waitcnt vmcnt(2)" ::: "memory"); } while (0)
#define VM0  asm volatile("s_waitcnt vmcnt(0)" ::: "memory")

  const int NTILE = K >> 6;
  const int NIT   = K >> 7;

  // ---- prologue: stage tiles 0 and 1 in steady-state FIFO order {B0, B1[,B2], A0-3} ----
  STG(4, 0); STG(5, 0);
  if constexpr (NT == 3) STG(6, 0);
  STG(0, 0); STG(1, 0); STG(2, 0); STG(3, 0);
  STG(4, 1); STG(5, 1);
  if constexpr (NT == 3) STG(6, 1);
  STG(0, 1); STG(1, 1); STG(2, 1); STG(3, 1);
  W2;                                // drains all of tile0; leaves tile1 (4+NT) in flight
  BARX;                              // tile0 globally visible
  LDA_(0, 0); LDB0_(0, bf0E);        // tile0 first-quadrant fragments (pre-issued)

  for (int i = 0; i < NIT; ++i) {
    const int t0 = 2 * i, t1 = 2 * i + 1;
    const int T2 = (t0 + 2 < NTILE) ? t0 + 2 : NTILE - 1;   // tail: benign identical restage
    const int T3 = (t1 + 2 < NTILE) ? t1 + 2 : NTILE - 1;
    // ================= frame t0 (bf0 cur = E) =================
    LDB1_(t0);
    MMAB0(0, bf0E); BARX;                        // ph1: (a0,b0)
    LDA_(t0, 1); STG(4, T2); W2;
    MMAB1(0); BARX;                              // ph2: (a0,b1)
    LDB0_(t1, bf0O); STG(5, T2);
    if constexpr (NT == 3) STG(6, T2);
    W3;
    MMAB1(1); BARX;                              // ph3: (a1,b1)
    LDA_(t1, 0); STG(0, T2); STG(1, T2); STG(2, T2); STG(3, T2);
    MMAB0(1, bf0E); BARX;                        // ph4: (a1,b0)
    // ================= frame t1 (bf0 cur = O) =================
    LDB1_(t1);
    MMAB0(0, bf0O); BARX;                        // ph1
    LDA_(t1, 1); STG(4, T3); W2;
    MMAB1(0); BARX;                              // ph2
    LDB0_(T2, bf0E); STG(5, T3);
    if constexpr (NT == 3) STG(6, T3);
    W3;
    MMAB1(1); BARX;                              // ph3
    LDA_(T2, 0); STG(0, T3); STG(1, T3); STG(2, T3); STG(3, T3);
    MMAB0(1, bf0O); BARX;                        // ph4
  }
  VM0;   // drain tail prefetch DMAs before LDS dealloc at wave exit

  if constexpr (MODE == 1) {
    // ---------- pure-register epilogue: RoPE (interleaved pairs) or V-transpose ----------
#pragma unroll
    for (int a = 0; a < 2; ++a)
#pragma unroll
      for (int b = 0; b < 2; ++b)
#pragma unroll
        for (int mt = 0; mt < 2; ++mt)
#pragma unroll
          for (int nt = 0; nt < NT; ++nt) {
            const int cb   = n0 + b * (NT * 32) + wc * (NT * 16) + nt * 16;
            const int row0 = m0 + wr * 64 + a * 32 + mt * 16 + quad * 4;
            if (cb >= 5120) {
              // V chunk: register transpose into vt[kv][d][s]
              const int dcol = cb + l15 - 5120;
              h16x4 vvv;
#pragma unroll
              for (int r = 0; r < 4; ++r) vvv[r] = (h16)acc[a][b][mt][nt][r];
              *(h16x4*)(vt + (size_t)dcol * SEQ + row0) = vvv;
            } else {
              // q/k chunk: RoPE with partner = lane^1 (interleaved-pair permutation).
              // q columns (cb<4096) additionally absorb 1/sqrt(HD) so flash skips it.
              const float qs = (cb < 4096) ? 0.08838834764831845f : 1.0f;
              const int col = cb + l15;
              const int j   = (col & 127) >> 1;
              const float sgn = (col & 1) ? 1.f : -1.f;
#pragma unroll
              for (int r = 0; r < 4; ++r) {
                float own = acc[a][b][mt][nt][r];
                float par = dpp_mv<0xB1>(own);               // quad_perm(1,0,3,2): lane^1
                float cc  = cosb[(size_t)(row0 + r) * 64 + j];
                float ss  = sinb[(size_t)(row0 + r) * 64 + j];
                C[(size_t)(row0 + r) * N + col] = (OutT)((own * cc + sgn * par * ss) * qs);
              }
            }
          }
  } else {
    // plain store
#pragma unroll
    for (int a = 0; a < 2; ++a)
#pragma unroll
      for (int b = 0; b < 2; ++b)
#pragma unroll
        for (int mt = 0; mt < 2; ++mt)
#pragma unroll
          for (int nt = 0; nt < NT; ++nt)
#pragma unroll
            for (int r = 0; r < 4; ++r) {
              int row = m0 + wr * 64 + a * 32 + mt * 16 + quad * 4 + r;
              int col = n0 + b * (NT * 32) + wc * (NT * 16) + nt * 16 + l15;
              C[(size_t)row * N + col] = (OutT)acc[a][b][mt][nt][r];
            }
  }
#undef STG
#undef LDA_
#undef LDB1_
#undef LDB0_
#undef MMAB1
#undef MMAB0
#undef CFENCE
#undef BARX
#undef W2
#undef W3
#undef VM0
}

// ---------- flash attention: block = (h, y), 128 q-rows, 4 waves x 32 rows, BK=64 ----------
// T14 async staging: K/V tile kt+1 is global_load'ed into REGISTERS right after
// tile kt is published; the reg->LDS write happens after the next read-done
// barrier, so HBM/L2 latency hides under tile kt's compute.  Mask work runs only
// on diagonal tiles; defer-max (THR=8) skips the rescale when the running max
// barely grows; 1/sqrt(HD) is pre-folded into q by the QKV epilogue.
__global__ __launch_bounds__(256, 2) void flash_attn(
    const h16* __restrict__ qkv, const h16* __restrict__ vt, h16* __restrict__ o_out) {
  __shared__ __attribute__((aligned(16))) h16 Ks[64 * 128];
  __shared__ __attribute__((aligned(16))) h16 Vts[128 * 64];
  __shared__ __attribute__((aligned(16))) h16 Ps[4][32 * 72];

  const int tid  = threadIdx.x;
  const int w    = tid >> 6, lane = tid & 63;
  const int quad = lane >> 4, l15 = lane & 15;
  const int h    = blockIdx.x;
  const int y    = blockIdx.y;
  const int qt   = (y < 8) ? (15 - y) : (y - 8);   // balanced heavy/light pairing
  const int kv   = h >> 2;
  const int rowq = qt * 128 + w * 32;
  const h16* vtg = vt + (size_t)kv * HD * SEQ;

  h16x8 qf[2][4];
#pragma unroll
  for (int mt = 0; mt < 2; ++mt) {
    const h16* qrow = qkv + (size_t)(rowq + mt * 16 + l15) * QKVD + h * 128;
#pragma unroll
    for (int ks = 0; ks < 4; ++ks)
      qf[mt][ks] = *(const h16x8*)(qrow + ks * 32 + quad * 8);
  }

  f32x4 o[2][8];
#pragma unroll
  for (int mt = 0; mt < 2; ++mt)
#pragma unroll
    for (int i = 0; i < 8; ++i) o[mt][i] = (f32x4){0.f, 0.f, 0.f, 0.f};
  float mrow[2][4], lrow[2][4];
#pragma unroll
  for (int mt = 0; mt < 2; ++mt)
#pragma unroll
    for (int r = 0; r < 4; ++r) { mrow[mt][r] = -3e30f; lrow[mt][r] = 0.f; }
  h16* Psw = Ps[w];

  // staging registers for tile kt+1 (static indexing only)
  h16x8 kreg[4], vreg[4];
#define LOADT(k0_) do {                                                              \
    _Pragma("unroll") for (int i = 0; i < 4; ++i) {                                  \
      int c = i * 256 + tid; int key = c >> 4, d8s = c & 15;                         \
      kreg[i] = *(const h16x8*)(qkv + (size_t)((k0_) + key) * QKVD + 4096 +          \
                                kv * 128 + ((d8s ^ (key & 15)) * 8));                \
    }                                                                                \
    _Pragma("unroll") for (int i = 0; i < 4; ++i) {                                  \
      int c = i * 256 + tid; int d = c >> 3, p = c & 7;                              \
      vreg[i] = *(const h16x8*)(vtg + (size_t)d * SEQ + (k0_) + ((p ^ (d & 7)) * 8));\
    }                                                                                \
  } while (0)

  const int nkt = 2 * qt + 2;
  LOADT(0);                         // prologue: tile 0 -> regs
  for (int kt = 0; kt < nkt; ++kt) {
    const int k0 = kt * 64;
    __syncthreads();                // all waves done reading previous tile's LDS
    // reg -> LDS (compiler inserts the vmcnt wait on kreg/vreg here)
#pragma unroll
    for (int i = 0; i < 4; ++i) *(h16x8*)((char*)Ks + (i * 256 + tid) * 16) = kreg[i];
#pragma unroll
    for (int i = 0; i < 4; ++i) *(h16x8*)((char*)Vts + (i * 256 + tid) * 16) = vreg[i];
    __syncthreads();                // publish tile kt
    const int knx = (kt + 1 < nkt) ? (kt + 1) * 64 : k0;   // clamp: benign refetch
    LOADT(knx);                     // issue next tile's loads; drain under compute

    if (k0 <= rowq + 31) {
      float alpha[2][4];
      f32x4 s2[2][4];
#pragma unroll
      for (int nt = 0; nt < 4; ++nt) {
        int key = nt * 16 + l15;
        f32x4 a0 = (f32x4){0.f, 0.f, 0.f, 0.f};
        f32x4 a1 = (f32x4){0.f, 0.f, 0.f, 0.f};
#pragma unroll
        for (int ks = 0; ks < 4; ++ks) {
          int d8 = ks * 4 + quad;
          h16x8 kf = *(const h16x8*)&Ks[key * 128 + ((d8 ^ (key & 15)) * 8)];
          a0 = __builtin_amdgcn_mfma_f32_16x16x32_f16(qf[0][ks], kf, a0, 0, 0, 0);
          a1 = __builtin_amdgcn_mfma_f32_16x16x32_f16(qf[1][ks], kf, a1, 0, 0, 0);
        }
        s2[0][nt] = a0;
        s2[1][nt] = a1;
      }
      // ---- row maxima (mask only on diagonal tiles), defer-max decision ----
      const bool needmask = (k0 + 63 > rowq);      // wave-uniform
      float tm2[2][4];
      float need = -3e30f;
#pragma unroll
      for (int mt = 0; mt < 2; ++mt) {
#pragma unroll
        for (int r = 0; r < 4; ++r) {
          float tm = -3e30f;
          if (needmask) {
            int rowg = rowq + mt * 16 + quad * 4 + r;
#pragma unroll
            for (int nt = 0; nt < 4; ++nt) {
              float v = s2[mt][nt][r];
              if (k0 + nt * 16 + l15 > rowg) v = -3e30f;
              s2[mt][nt][r] = v;
              tm = fmaxf(tm, v);
            }
          } else {
#pragma unroll
            for (int nt = 0; nt < 4; ++nt) tm = fmaxf(tm, s2[mt][nt][r]);
          }
          tm = red16_max(tm);
          tm2[mt][r] = tm;
          need = fmaxf(need, tm - mrow[mt][r]);
        }
      }
      if (__any(need > 8.0f)) {       // T13: rescale only when max grew past THR
#pragma unroll
        for (int mt = 0; mt < 2; ++mt)
#pragma unroll
          for (int r = 0; r < 4; ++r) {
            float mnew = fmaxf(mrow[mt][r], tm2[mt][r]);
            alpha[mt][r] = __expf(mrow[mt][r] - mnew);
            mrow[mt][r] = mnew;
          }
#pragma unroll
        for (int mt = 0; mt < 2; ++mt)
#pragma unroll
          for (int on = 0; on < 8; ++on) {
            o[mt][on][0] *= alpha[mt][0]; o[mt][on][1] *= alpha[mt][1];
            o[mt][on][2] *= alpha[mt][2]; o[mt][on][3] *= alpha[mt][3];
          }
#pragma unroll
        for (int mt = 0; mt < 2; ++mt)
#pragma unroll
          for (int r = 0; r < 4; ++r) lrow[mt][r] *= alpha[mt][r];
      }
      // ---- exp + P store + row sums (P bounded by e^THR, fine in h16/f32) ----
#pragma unroll
      for (int mt = 0; mt < 2; ++mt) {
#pragma unroll
        for (int r = 0; r < 4; ++r) {
          float m = mrow[mt][r];
          float ps = 0.f;
#pragma unroll
          for (int nt = 0; nt < 4; ++nt) {
            float e = __expf(s2[mt][nt][r] - m);
            ps += e;
            Psw[(mt * 16 + quad * 4 + r) * 72 + nt * 16 + l15] = (h16)e;
          }
          ps = red16_sum(ps);
          lrow[mt][r] += ps;
        }
      }
      asm volatile("s_waitcnt lgkmcnt(0)" ::: "memory");
#pragma unroll
      for (int ks = 0; ks < 2; ++ks) {
        h16x8 pf0 = *(const h16x8*)&Psw[(0  + l15) * 72 + ks * 32 + quad * 8];
        h16x8 pf1 = *(const h16x8*)&Psw[(16 + l15) * 72 + ks * 32 + quad * 8];
        int k8 = ks * 4 + quad;
#pragma unroll
        for (int on = 0; on < 8; ++on) {
          int d = on * 16 + l15;
          h16x8 vf = *(const h16x8*)&Vts[d * 64 + ((k8 ^ (d & 7)) * 8)];
          o[0][on] = __builtin_amdgcn_mfma_f32_16x16x32_f16(pf0, vf, o[0][on], 0, 0, 0);
          o[1][on] = __builtin_amdgcn_mfma_f32_16x16x32_f16(pf1, vf, o[1][on], 0, 0, 0);
        }
      }
    }
  }
#undef LOADT
#pragma unroll
  for (int mt = 0; mt < 2; ++mt) {
    float linv[4];
#pragma unroll
    for (int r = 0; r < 4; ++r) linv[r] = 1.0f / lrow[mt][r];
#pragma unroll
    for (int on = 0; on < 8; ++on)
#pragma unroll
      for (int r = 0; r < 4; ++r) {
        int row = rowq + mt * 16 + quad * 4 + r;
        int col = h * 128 + on * 16 + l15;
        o_out[(size_t)row * DIMX + col] = (h16)(o[mt][on][r] * linv[r]);
      }
  }
}

extern "C" void kernel_launch(void* const* d_in, const int* in_sizes, int n_in,
                              void* d_out, int out_size, void* d_ws, size_t ws_size,
                              hipStream_t stream) {
  const float* x    = (const float*)d_in[0];
  const void*  wq   = d_in[1];
  const float* sq   = (const float*)d_in[2];
  const void*  wk   = d_in[3];
  const float* sk   = (const float*)d_in[4];
  const void*  wv   = d_in[5];
  const float* sv   = (const float*)d_in[6];
  const void*  wo   = d_in[7];
  const float* so   = (const float*)d_in[8];
  const float* cosb = (const float*)d_in[9];
  const float* sinb = (const float*)d_in[10];
  float* out = (float*)d_out;

  char* ws = (char*)d_ws;
  h16* Wqkv = (h16*)ws;                      // 6144*4096 h16 = 50331648 B
  h16* Wo   = (h16*)(ws + 50331648);         // 4096*4096 h16 = 33554432 B
  h16* xb   = (h16*)(ws + 83886080);         // x as h16; later attn_out
  h16* qkv  = (h16*)(ws + 100663296);        // 2048*6144 h16
  h16* vt   = (h16*)d_out;                   // vt scratch lives in d_out (dead until O-proj)

  // fused dequant (wq,wk: RoPE-pair-interleaved rows; wv,wo plain) + cast(x)
  prep_all<<<28672, 256, 0, stream>>>(wq, sq, wk, sk, wv, sv, wo, so,
                                      (const float4*)x, Wqkv, Wo, (h16x4*)xb);

  // qkv = x @ Wqkv^T, 256x192 pipelined schedule (256 blocks = 1/CU),
  // fused register RoPE (q: +1/sqrt(HD)) + direct V-transpose
  gemm_pipe<h16, 3, 1><<<dim3(32, 8), 512, 0, stream>>>(
      xb, Wqkv, qkv, QKVD, DIMX, cosb, sinb, vt);

  // flash attention (T14 async reg-staging) -> attn_out (reuse xb region)
  flash_attn<<<dim3(32, 16), 256, 0, stream>>>(qkv, vt, xb);

  // out = attn_out @ Wo^T, 256x128 pipelined schedule (256 blocks = 1/CU)
  gemm_pipe<float, 2, 0><<<dim3(32, 8), 512, 0, stream>>>(
      xb, Wo, out, DIMX, DIMX, cosb, sinb, vt);
}